// Round 1
// baseline (1461.777 us; speedup 1.0000x reference)
//
#include <hip/hip_runtime.h>

#define N_NODES 100000
#define N_EDGES 800000
#define NG      64
#define NPAD    100096   // 782 * 128

// ---------------- workspace layout (bytes) ----------------
constexpr size_t OFF_AGG1 = 0;                              // N f32 (400000)
constexpr size_t OFF_DEG  = OFF_AGG1 + 400128;              // N i32
constexpr size_t OFF_ROW  = OFF_DEG  + 400128;              // N i32
constexpr size_t OFF_CUR  = OFF_ROW  + 400128;              // N i32
constexpr size_t OFF_PART = OFF_CUR  + 400128;              // 128 i32
constexpr size_t OFF_CSR  = OFF_PART + 512;                 // E i32 (3200000)
constexpr size_t OFF_XCAT = OFF_CSR  + 3200000;             // NPAD*256 bf16
constexpr size_t OFF_H2   = OFF_XCAT + (size_t)NPAD*256*2;  // NPAD*256 bf16
constexpr size_t OFF_WT   = OFF_H2   + (size_t)NPAD*256*2;  // 256*256 bf16
constexpr size_t OFF_PH2  = OFF_WT   + 256*256*2;           // 64*256 f32
constexpr size_t OFF_PAGG = OFF_PH2  + (size_t)NG*256*4;    // 64*256 f32
constexpr size_t OFF_CNT  = OFF_PAGG + (size_t)NG*256*4;    // 64 f32

typedef __attribute__((ext_vector_type(8))) short bf16x8;
typedef __attribute__((ext_vector_type(4))) float f32x4;

__device__ __forceinline__ float bfu2f(unsigned short u) {
    return __uint_as_float(((unsigned)u) << 16);
}
__device__ __forceinline__ unsigned short f2bfu(float f) {
    unsigned u = __float_as_uint(f);
    unsigned r = (u + 0x7FFFu + ((u >> 16) & 1u)) >> 16;   // RNE
    return (unsigned short)r;
}

// ---- layer-1 scalar aggregation + degree histogram (one edge pass) ----
__global__ void k_edge1(const float* __restrict__ x, const int* __restrict__ src,
                        const int* __restrict__ dst, float* agg1, int* deg) {
    int e = blockIdx.x * 256 + threadIdx.x;
    if (e >= N_EDGES) return;
    int s = src[e], d = dst[e];
    atomicAdd(&agg1[d], x[s]);
    atomicAdd(&deg[d], 1);
}

// ---- h1 = relu(a*u + x*v + b) -> Xcat[:,128:256] (bf16) ----
__global__ void k_h1(const float* __restrict__ agg1, const float* __restrict__ x,
                     const float* __restrict__ Wr1, const float* __restrict__ Wo1,
                     const float* __restrict__ br1, unsigned short* __restrict__ xcat) {
    int gid = blockIdx.x * 256 + threadIdx.x;
    if (gid >= NPAD * 128) return;
    int i = gid >> 7, d = gid & 127;
    float v = 0.f;
    if (i < N_NODES)
        v = fmaxf(fmaf(agg1[i], Wr1[d], fmaf(x[i], Wo1[d], br1[d])), 0.f);
    xcat[(size_t)i * 256 + 128 + d] = f2bfu(v);
}

// ---- CSR build: block scan / partial scan / offsets / scatter ----
__global__ __launch_bounds__(1024) void k_scanA(const int* __restrict__ deg, int* rowst, int* part) {
    __shared__ int sm[1024];
    int t = threadIdx.x, i = blockIdx.x * 1024 + t;
    int v = (i < N_NODES) ? deg[i] : 0;
    sm[t] = v; __syncthreads();
    for (int o = 1; o < 1024; o <<= 1) {
        int y = (t >= o) ? sm[t - o] : 0;
        __syncthreads();
        sm[t] += y;
        __syncthreads();
    }
    if (i < N_NODES) rowst[i] = sm[t] - v;
    if (t == 1023) part[blockIdx.x] = sm[t];
}
__global__ void k_scanB(int* part) {   // 1 block, 128 threads; NB = 98
    __shared__ int sm[128];
    int t = threadIdx.x;
    int v = (t < 98) ? part[t] : 0;
    sm[t] = v; __syncthreads();
    for (int o = 1; o < 128; o <<= 1) {
        int y = (t >= o) ? sm[t - o] : 0;
        __syncthreads();
        sm[t] += y;
        __syncthreads();
    }
    if (t < 98) part[t] = sm[t] - v;
}
__global__ void k_scanC(int* rowst, int* cur, const int* __restrict__ part) {
    int i = blockIdx.x * 256 + threadIdx.x;
    if (i >= N_NODES) return;
    int r = rowst[i] + part[i >> 10];
    rowst[i] = r; cur[i] = r;
}
__global__ void k_scatter(const int* __restrict__ src, const int* __restrict__ dst,
                          int* cur, int* csr) {
    int e = blockIdx.x * 256 + threadIdx.x;
    if (e >= N_EDGES) return;
    int p = atomicAdd(&cur[dst[e]], 1);
    csr[p] = src[e];
}

// ---- agg2 via CSR: per-edge recompute h1[src] from 2 scalars, fp32 regs ----
__global__ __launch_bounds__(256) void k_agg2(const float* __restrict__ agg1, const float* __restrict__ x,
                                              const int* __restrict__ rowst, const int* __restrict__ deg,
                                              const int* __restrict__ csr,
                                              const float* __restrict__ Wr1, const float* __restrict__ Wo1,
                                              const float* __restrict__ br1, unsigned int* __restrict__ xcat_u32) {
    const int wave = threadIdx.x >> 6, lane = threadIdx.x & 63;
    const int d0 = 2 * lane, d1 = 2 * lane + 1;
    const float u0 = Wr1[d0], u1 = Wr1[d1];
    const float v0 = Wo1[d0], v1 = Wo1[d1];
    const float c0 = br1[d0], c1 = br1[d1];
    int wid = blockIdx.x * 4 + wave;
    int nw = gridDim.x * 4;
    for (int i = wid; i < NPAD; i += nw) {
        float a0 = 0.f, a1 = 0.f;
        if (i < N_NODES) {
            int dg = deg[i], st = rowst[i];
            for (int base = 0; base < dg; base += 64) {
                float av = 0.f, xv = 0.f;
                int e = base + lane;
                if (e < dg) { int s = csr[st + e]; av = agg1[s]; xv = x[s]; }
                int cnt = min(64, dg - base);
                for (int j = 0; j < cnt; ++j) {
                    float aj = __shfl(av, j);
                    float xj = __shfl(xv, j);
                    a0 += fmaxf(fmaf(aj, u0, fmaf(xj, v0, c0)), 0.f);
                    a1 += fmaxf(fmaf(aj, u1, fmaf(xj, v1, c1)), 0.f);
                }
            }
        }
        unsigned int w = (unsigned)f2bfu(a0) | ((unsigned)f2bfu(a1) << 16);
        xcat_u32[(size_t)i * 128 + lane] = w;
    }
}

// ---- Wcat^T (bf16): Wt[c][k] = (k<128 ? W_rel2[k][c] : W_root2[k-128][c]) ----
__global__ void k_wt(const float* __restrict__ Wr2, const float* __restrict__ Wo2,
                     unsigned short* __restrict__ Wt) {
    int gid = blockIdx.x * 256 + threadIdx.x;   // 65536
    int k = gid & 255, c = gid >> 8;
    float v = (k < 128) ? Wr2[k * 256 + c] : Wo2[(k - 128) * 256 + c];
    Wt[c * 256 + k] = f2bfu(v);
}

// ---- layer-2 GEMM: h2 = relu(Xcat @ Wcat + b2), bf16 MFMA, no LDS ----
__global__ __launch_bounds__(256) void k_gemm(const short* __restrict__ Xcat, const short* __restrict__ Wt,
                                              const float* __restrict__ b2, unsigned short* __restrict__ h2) {
    const int wave = threadIdx.x >> 6, lane = threadIdx.x & 63;
    const int row0 = blockIdx.x * 128 + wave * 32;
    const int lr = lane & 15;
    const int lk = (lane >> 4) << 3;          // 0,8,16,24
    f32x4 acc[2][16];
    #pragma unroll
    for (int h = 0; h < 2; ++h)
        #pragma unroll
        for (int t = 0; t < 16; ++t) acc[h][t] = (f32x4){0.f, 0.f, 0.f, 0.f};
    const short* aptr0 = Xcat + (size_t)(row0 + lr) * 256 + lk;
    const short* aptr1 = aptr0 + 16 * 256;
    const short* bptr  = Wt + (size_t)lr * 256 + lk;
    #pragma unroll
    for (int k0 = 0; k0 < 256; k0 += 32) {
        bf16x8 a0 = *(const bf16x8*)(aptr0 + k0);
        bf16x8 a1 = *(const bf16x8*)(aptr1 + k0);
        #pragma unroll
        for (int t = 0; t < 16; ++t) {
            bf16x8 b = *(const bf16x8*)(bptr + t * 16 * 256 + k0);
            acc[0][t] = __builtin_amdgcn_mfma_f32_16x16x32_bf16(a0, b, acc[0][t], 0, 0, 0);
            acc[1][t] = __builtin_amdgcn_mfma_f32_16x16x32_bf16(a1, b, acc[1][t], 0, 0, 0);
        }
    }
    const int rbase = (lane >> 4) * 4;
    #pragma unroll
    for (int h = 0; h < 2; ++h) {
        int rb = row0 + h * 16 + rbase;
        #pragma unroll
        for (int t = 0; t < 16; ++t) {
            int col = t * 16 + lr;
            float bias = b2[col];
            #pragma unroll
            for (int j = 0; j < 4; ++j) {
                float v = fmaxf(acc[h][t][j] + bias, 0.f);
                h2[(size_t)(rb + j) * 256 + col] = f2bfu(v);
            }
        }
    }
}

// ---- P_h2[g] = sum over nodes of h2 (batch sorted -> segment chunks) ----
__global__ __launch_bounds__(256) void k_pool_h2(const unsigned short* __restrict__ h2,
                                                 const int* __restrict__ batch,
                                                 float* Ph2, float* cntf) {
    __shared__ int sb[128];
    int i0 = blockIdx.x * 128;
    int len = min(128, N_NODES - i0);
    int t = threadIdx.x;
    if (t < 128) sb[t] = (t < len) ? batch[i0 + t] : -1;
    __syncthreads();
    int s = 0;
    while (s < len) {
        int g = sb[s];
        int e = s + 1;
        while (e < len && sb[e] == g) ++e;
        float acc = 0.f;
        for (int i = s; i < e; ++i) acc += bfu2f(h2[(size_t)(i0 + i) * 256 + t]);
        atomicAdd(&Ph2[g * 256 + t], acc);
        if (t == 0) atomicAdd(&cntf[g], (float)(e - s));
        s = e;
    }
}

// ---- P_agg[g] = sum over edges (batch[dst]==g) of h2[src]; LDS [64][256] ----
__global__ __launch_bounds__(256) void k_pool_agg3(const unsigned short* __restrict__ h2,
                                                   const int* __restrict__ src, const int* __restrict__ dst,
                                                   const int* __restrict__ batch, float* Pagg) {
    __shared__ float lacc[NG * 256];   // 64 KB
    for (int i = threadIdx.x; i < NG * 256; i += 256) lacc[i] = 0.f;
    __syncthreads();
    const int wave = threadIdx.x >> 6, lane = threadIdx.x & 63;
    const int wid = blockIdx.x * 4 + wave;
    const int nw = gridDim.x * 4;
    for (int b = wid * 4; b < N_EDGES; b += nw * 4) {
        int sA[4], gA[4];
        #pragma unroll
        for (int u = 0; u < 4; ++u) {
            int e = b + u;
            sA[u] = (e < N_EDGES) ? src[e] : -1;
        }
        #pragma unroll
        for (int u = 0; u < 4; ++u) {
            int e = b + u;
            gA[u] = (e < N_EDGES) ? batch[dst[e]] : 0;
        }
        float v[4][4];
        #pragma unroll
        for (int u = 0; u < 4; ++u) {
            if (sA[u] >= 0) {
                const unsigned short* rp = h2 + (size_t)sA[u] * 256;
                v[u][0] = bfu2f(rp[lane]);
                v[u][1] = bfu2f(rp[lane + 64]);
                v[u][2] = bfu2f(rp[lane + 128]);
                v[u][3] = bfu2f(rp[lane + 192]);
            }
        }
        #pragma unroll
        for (int u = 0; u < 4; ++u) {
            if (sA[u] >= 0) {
                float* lr = lacc + gA[u] * 256;   // bank = lane%32 -> 2-way, free
                atomicAdd(lr + lane,       v[u][0]);
                atomicAdd(lr + lane + 64,  v[u][1]);
                atomicAdd(lr + lane + 128, v[u][2]);
                atomicAdd(lr + lane + 192, v[u][3]);
            }
        }
    }
    __syncthreads();
    for (int i = threadIdx.x; i < NG * 256; i += 256) atomicAdd(&Pagg[i], lacc[i]);
}

// ---- layer-3 on pooled sums + mean + L2 normalize ----
__global__ __launch_bounds__(256) void k_final(const float* __restrict__ Pagg, const float* __restrict__ Ph2,
                                               const float* __restrict__ cntf,
                                               const float* __restrict__ Wr3, const float* __restrict__ br3,
                                               const float* __restrict__ Wo3, float* __restrict__ out) {
    __shared__ float sa[256], sh[256];
    __shared__ float wred[4];
    int g = blockIdx.x, t = threadIdx.x;
    sa[t] = Pagg[g * 256 + t];
    sh[t] = Ph2[g * 256 + t];
    __syncthreads();
    float c0 = 0.f, c1 = 0.f;
    #pragma unroll 4
    for (int k = 0; k < 256; ++k) {
        float a = sa[k], h = sh[k];
        c0 = fmaf(a, Wr3[k * 512 + t], c0);
        c0 = fmaf(h, Wo3[k * 512 + t], c0);
        c1 = fmaf(a, Wr3[k * 512 + t + 256], c1);
        c1 = fmaf(h, Wo3[k * 512 + t + 256], c1);
    }
    float cnt = cntf[g];
    float inv = 1.f / fmaxf(cnt, 1.f);
    float p0 = (c0 + cnt * br3[t]) * inv;
    float p1 = (c1 + cnt * br3[t + 256]) * inv;
    float ss = p0 * p0 + p1 * p1;
    for (int o = 32; o > 0; o >>= 1) ss += __shfl_down(ss, o);
    int wv = t >> 6, lane = t & 63;
    if (lane == 0) wred[wv] = ss;
    __syncthreads();
    float tot = wred[0] + wred[1] + wred[2] + wred[3];
    float inv2 = 1.f / fmaxf(sqrtf(tot), 1e-12f);
    out[g * 512 + t]       = p0 * inv2;
    out[g * 512 + t + 256] = p1 * inv2;
}

extern "C" void kernel_launch(void* const* d_in, const int* in_sizes, int n_in,
                              void* d_out, int out_size, void* d_ws, size_t ws_size,
                              hipStream_t stream) {
    const float* x   = (const float*)d_in[0];
    const int*   ei  = (const int*)d_in[1];
    const int*   bat = (const int*)d_in[2];
    const float* Wr1 = (const float*)d_in[3];
    const float* br1 = (const float*)d_in[4];
    const float* Wo1 = (const float*)d_in[5];
    const float* Wr2 = (const float*)d_in[6];
    const float* br2 = (const float*)d_in[7];
    const float* Wo2 = (const float*)d_in[8];
    const float* Wr3 = (const float*)d_in[9];
    const float* br3 = (const float*)d_in[10];
    const float* Wo3 = (const float*)d_in[11];
    const int* src = ei;
    const int* dst = ei + N_EDGES;

    char* ws = (char*)d_ws;
    float*          agg1 = (float*)(ws + OFF_AGG1);
    int*            deg  = (int*)(ws + OFF_DEG);
    int*            rowst= (int*)(ws + OFF_ROW);
    int*            cur  = (int*)(ws + OFF_CUR);
    int*            part = (int*)(ws + OFF_PART);
    int*            csr  = (int*)(ws + OFF_CSR);
    unsigned short* xcat = (unsigned short*)(ws + OFF_XCAT);
    unsigned short* h2   = (unsigned short*)(ws + OFF_H2);
    unsigned short* wt   = (unsigned short*)(ws + OFF_WT);
    float*          Ph2  = (float*)(ws + OFF_PH2);
    float*          Pagg = (float*)(ws + OFF_PAGG);
    float*          cntf = (float*)(ws + OFF_CNT);

    hipMemsetAsync(agg1, 0, N_NODES * 4, stream);
    hipMemsetAsync(deg, 0, N_NODES * 4, stream);
    hipMemsetAsync(ws + OFF_PH2, 0, (size_t)NG * 256 * 4 * 2 + 256, stream);

    k_edge1<<<(N_EDGES + 255) / 256, 256, 0, stream>>>(x, src, dst, agg1, deg);
    k_h1<<<(NPAD * 128) / 256, 256, 0, stream>>>(agg1, x, Wr1, Wo1, br1, xcat);
    k_scanA<<<98, 1024, 0, stream>>>(deg, rowst, part);
    k_scanB<<<1, 128, 0, stream>>>(part);
    k_scanC<<<(N_NODES + 255) / 256, 256, 0, stream>>>(rowst, cur, part);
    k_scatter<<<(N_EDGES + 255) / 256, 256, 0, stream>>>(src, dst, cur, csr);
    k_agg2<<<1024, 256, 0, stream>>>(agg1, x, rowst, deg, csr, Wr1, Wo1, br1, (unsigned int*)xcat);
    k_wt<<<256, 256, 0, stream>>>(Wr2, Wo2, wt);
    k_gemm<<<NPAD / 128, 256, 0, stream>>>((const short*)xcat, (const short*)wt, br2, h2);
    k_pool_h2<<<(N_NODES + 127) / 128, 256, 0, stream>>>(h2, bat, Ph2, cntf);
    k_pool_agg3<<<512, 256, 0, stream>>>(h2, src, dst, bat, Pagg);
    k_final<<<NG, 256, 0, stream>>>(Pagg, Ph2, cntf, Wr3, br3, Wo3, (float*)d_out);
}

// Round 3
// 532.598 us; speedup vs baseline: 2.7446x; 2.7446x over previous
//
#include <hip/hip_runtime.h>

#define N_NODES 100000
#define N_EDGES 800000
#define NG      64
#define NPAD    100096   // 782 * 128 = 391 * 256

// ---------------- workspace layout (bytes) ----------------
constexpr size_t OFF_AGG1 = 0;                              // N f32
constexpr size_t OFF_DEG  = OFF_AGG1 + 400128;              // N i32
constexpr size_t OFF_ROW  = OFF_DEG  + 400128;              // N i32
constexpr size_t OFF_CUR  = OFF_ROW  + 400128;              // N i32
constexpr size_t OFF_PART = OFF_CUR  + 400128;              // 128 i32
constexpr size_t OFF_CSR  = OFF_PART + 512;                 // E i32
constexpr size_t OFF_XCAT = OFF_CSR  + 3200000;             // NPAD*256 bf16 = 51,249,152 B
// after k_gemm, XCAT region is reused:
constexpr size_t OFF_MT   = OFF_XCAT;                       // 64*NPAD f32   = 25,624,576 B
constexpr size_t OFF_MTB  = OFF_XCAT + 25624576;            // 128*NPAD bf16 = 25,624,576 B
constexpr size_t OFF_H2T  = OFF_XCAT + (size_t)NPAD*256*2;  // 256*NPAD bf16 (transposed h2)
constexpr size_t OFF_WT   = OFF_H2T  + (size_t)NPAD*256*2;  // 256*256 bf16
constexpr size_t OFF_PCAT = OFF_WT   + 256*256*2;           // 128*256 f32
constexpr size_t OFF_CNT  = OFF_PCAT + 128*256*4;           // 64 f32

typedef __attribute__((ext_vector_type(8))) short bf16x8;
typedef __attribute__((ext_vector_type(8))) unsigned short u16x8;
typedef __attribute__((ext_vector_type(4))) unsigned short u16x4;
typedef __attribute__((ext_vector_type(4))) float f32x4;

__device__ __forceinline__ float bfu2f(unsigned short u) {
    return __uint_as_float(((unsigned)u) << 16);
}
__device__ __forceinline__ unsigned short f2bfu(float f) {
    unsigned u = __float_as_uint(f);
    unsigned r = (u + 0x7FFFu + ((u >> 16) & 1u)) >> 16;   // RNE
    return (unsigned short)r;
}

// ---- layer-1 scalar aggregation + degree histogram (one edge pass) ----
__global__ void k_edge1(const float* __restrict__ x, const int* __restrict__ src,
                        const int* __restrict__ dst, float* agg1, int* deg) {
    int e = blockIdx.x * 256 + threadIdx.x;
    if (e >= N_EDGES) return;
    int s = src[e], d = dst[e];
    atomicAdd(&agg1[d], x[s]);
    atomicAdd(&deg[d], 1);
}

// ---- h1 = relu(a*u + x*v + b) -> Xcat[:,128:256] (bf16) ----
__global__ void k_h1(const float* __restrict__ agg1, const float* __restrict__ x,
                     const float* __restrict__ Wr1, const float* __restrict__ Wo1,
                     const float* __restrict__ br1, unsigned short* __restrict__ xcat) {
    int gid = blockIdx.x * 256 + threadIdx.x;
    if (gid >= NPAD * 128) return;
    int i = gid >> 7, d = gid & 127;
    float v = 0.f;
    if (i < N_NODES)
        v = fmaxf(fmaf(agg1[i], Wr1[d], fmaf(x[i], Wo1[d], br1[d])), 0.f);
    xcat[(size_t)i * 256 + 128 + d] = f2bfu(v);
}

// ---- CSR build: block scan / partial scan / offsets / scatter ----
__global__ __launch_bounds__(1024) void k_scanA(const int* __restrict__ deg, int* rowst, int* part) {
    __shared__ int sm[1024];
    int t = threadIdx.x, i = blockIdx.x * 1024 + t;
    int v = (i < N_NODES) ? deg[i] : 0;
    sm[t] = v; __syncthreads();
    for (int o = 1; o < 1024; o <<= 1) {
        int y = (t >= o) ? sm[t - o] : 0;
        __syncthreads();
        sm[t] += y;
        __syncthreads();
    }
    if (i < N_NODES) rowst[i] = sm[t] - v;
    if (t == 1023) part[blockIdx.x] = sm[t];
}
__global__ void k_scanB(int* part) {   // 1 block, 128 threads; NB = 98
    __shared__ int sm[128];
    int t = threadIdx.x;
    int v = (t < 98) ? part[t] : 0;
    sm[t] = v; __syncthreads();
    for (int o = 1; o < 128; o <<= 1) {
        int y = (t >= o) ? sm[t - o] : 0;
        __syncthreads();
        sm[t] += y;
        __syncthreads();
    }
    if (t < 98) part[t] = sm[t] - v;
}
__global__ void k_scanC(int* rowst, int* cur, const int* __restrict__ part) {
    int i = blockIdx.x * 256 + threadIdx.x;
    if (i >= N_NODES) return;
    int r = rowst[i] + part[i >> 10];
    rowst[i] = r; cur[i] = r;
}
__global__ void k_scatter(const int* __restrict__ src, const int* __restrict__ dst,
                          int* cur, int* csr) {
    int e = blockIdx.x * 256 + threadIdx.x;
    if (e >= N_EDGES) return;
    int p = atomicAdd(&cur[dst[e]], 1);
    csr[p] = src[e];
}

// ---- agg2 via CSR: per-edge recompute h1[src] from 2 scalars, fp32 regs ----
__global__ __launch_bounds__(256) void k_agg2(const float* __restrict__ agg1, const float* __restrict__ x,
                                              const int* __restrict__ rowst, const int* __restrict__ deg,
                                              const int* __restrict__ csr,
                                              const float* __restrict__ Wr1, const float* __restrict__ Wo1,
                                              const float* __restrict__ br1, unsigned int* __restrict__ xcat_u32) {
    const int wave = threadIdx.x >> 6, lane = threadIdx.x & 63;
    const int d0 = 2 * lane, d1 = 2 * lane + 1;
    const float u0 = Wr1[d0], u1 = Wr1[d1];
    const float v0 = Wo1[d0], v1 = Wo1[d1];
    const float c0 = br1[d0], c1 = br1[d1];
    int wid = blockIdx.x * 4 + wave;
    int nw = gridDim.x * 4;
    for (int i = wid; i < NPAD; i += nw) {
        float a0 = 0.f, a1 = 0.f;
        if (i < N_NODES) {
            int dg = deg[i], st = rowst[i];
            for (int base = 0; base < dg; base += 64) {
                float av = 0.f, xv = 0.f;
                int e = base + lane;
                if (e < dg) { int s = csr[st + e]; av = agg1[s]; xv = x[s]; }
                int cnt = min(64, dg - base);
                for (int j = 0; j < cnt; ++j) {
                    float aj = __shfl(av, j);
                    float xj = __shfl(xv, j);
                    a0 += fmaxf(fmaf(aj, u0, fmaf(xj, v0, c0)), 0.f);
                    a1 += fmaxf(fmaf(aj, u1, fmaf(xj, v1, c1)), 0.f);
                }
            }
        }
        unsigned int w = (unsigned)f2bfu(a0) | ((unsigned)f2bfu(a1) << 16);
        xcat_u32[(size_t)i * 128 + lane] = w;
    }
}

// ---- Wcat^T (bf16): Wt[c][k] = (k<128 ? W_rel2[k][c] : W_root2[k-128][c]) ----
__global__ void k_wt(const float* __restrict__ Wr2, const float* __restrict__ Wo2,
                     unsigned short* __restrict__ Wt) {
    int gid = blockIdx.x * 256 + threadIdx.x;   // 65536
    int k = gid & 255, c = gid >> 8;
    float v = (k < 128) ? Wr2[k * 256 + c] : Wo2[(k - 128) * 256 + c];
    Wt[c * 256 + k] = f2bfu(v);
}

// ---- layer-2 GEMM: h2 = relu(Xcat @ Wcat + b2), bf16 MFMA; stores h2 TRANSPOSED ----
__global__ __launch_bounds__(256) void k_gemm(const short* __restrict__ Xcat, const short* __restrict__ Wt,
                                              const float* __restrict__ b2, unsigned short* __restrict__ h2t) {
    const int wave = threadIdx.x >> 6, lane = threadIdx.x & 63;
    const int row0 = blockIdx.x * 128 + wave * 32;
    const int lr = lane & 15;
    const int lk = (lane >> 4) << 3;          // 0,8,16,24
    f32x4 acc[2][16];
    #pragma unroll
    for (int h = 0; h < 2; ++h)
        #pragma unroll
        for (int t = 0; t < 16; ++t) acc[h][t] = (f32x4){0.f, 0.f, 0.f, 0.f};
    const short* aptr0 = Xcat + (size_t)(row0 + lr) * 256 + lk;
    const short* aptr1 = aptr0 + 16 * 256;
    const short* bptr  = Wt + (size_t)lr * 256 + lk;
    #pragma unroll
    for (int k0 = 0; k0 < 256; k0 += 32) {
        bf16x8 a0 = *(const bf16x8*)(aptr0 + k0);
        bf16x8 a1 = *(const bf16x8*)(aptr1 + k0);
        #pragma unroll
        for (int t = 0; t < 16; ++t) {
            bf16x8 b = *(const bf16x8*)(bptr + t * 16 * 256 + k0);
            acc[0][t] = __builtin_amdgcn_mfma_f32_16x16x32_bf16(a0, b, acc[0][t], 0, 0, 0);
            acc[1][t] = __builtin_amdgcn_mfma_f32_16x16x32_bf16(a1, b, acc[1][t], 0, 0, 0);
        }
    }
    const int rbase = (lane >> 4) * 4;
    #pragma unroll
    for (int h = 0; h < 2; ++h) {
        int rb = row0 + h * 16 + rbase;
        #pragma unroll
        for (int t = 0; t < 16; ++t) {
            int col = t * 16 + lr;
            float bias = b2[col];
            u16x4 w;
            #pragma unroll
            for (int j = 0; j < 4; ++j)
                w[j] = f2bfu(fmaxf(acc[h][t][j] + bias, 0.f));
            *(u16x4*)(h2t + (size_t)col * NPAD + rb) = w;   // transposed store, 8B/lane
        }
    }
}

// ---- count-matrix build: edges -> Mt (f32 atomics), rows 0..63 ----
__global__ void k_mbedges(const int* __restrict__ src, const int* __restrict__ dst,
                          const int* __restrict__ batch, float* __restrict__ mt) {
    int e = blockIdx.x * 256 + threadIdx.x;
    if (e >= N_EDGES) return;
    int g = batch[dst[e]];
    atomicAdd(&mt[(size_t)g * NPAD + src[e]], 1.f);
}

// ---- indicator rows 64..127 (bf16, direct store) + per-graph node counts ----
__global__ __launch_bounds__(256) void k_mbnodes(const int* __restrict__ batch,
                                                 unsigned short* __restrict__ mtb, float* cntf) {
    __shared__ float lc[NG];
    int t = threadIdx.x;
    if (t < NG) lc[t] = 0.f;
    __syncthreads();
    int i = blockIdx.x * 256 + t;
    if (i < N_NODES) {
        int g = batch[i];
        mtb[(size_t)(64 + g) * NPAD + i] = 0x3F80;   // bf16 1.0
        atomicAdd(&lc[g], 1.f);
    }
    __syncthreads();
    if (t < NG) atomicAdd(&cntf[t], lc[t]);
}

// ---- convert count rows f32 -> bf16 (rows 0..63 of Mtb) ----
__global__ void k_mconv(const float* __restrict__ mt, unsigned short* __restrict__ mtb) {
    size_t base = ((size_t)blockIdx.x * 256 + threadIdx.x) * 8;   // 64*NPAD total, exact
    f32x4 a = *(const f32x4*)(mt + base);
    f32x4 b = *(const f32x4*)(mt + base + 4);
    u16x8 w;
    #pragma unroll
    for (int j = 0; j < 4; ++j) { w[j] = f2bfu(a[j]); w[4 + j] = f2bfu(b[j]); }
    *(u16x8*)(mtb + base) = w;
}

// ---- pooling GEMM: Pcat[128][256] += Mtb[128][K-slice] @ h2t^T, MFMA ----
__global__ __launch_bounds__(256) void k_pool_gemm(const short* __restrict__ mtb,
                                                   const short* __restrict__ h2t,
                                                   float* __restrict__ pcat) {
    const int wave = threadIdx.x >> 6, lane = threadIdx.x & 63;
    const int row0 = wave * 32;               // 4 waves cover 128 channel-rows
    const int lr = lane & 15;
    const int lk = (lane >> 4) << 3;
    const int kbeg = blockIdx.x * 512;
    const int kend = min(kbeg + 512, NPAD);
    f32x4 acc[2][16];
    #pragma unroll
    for (int h = 0; h < 2; ++h)
        #pragma unroll
        for (int t = 0; t < 16; ++t) acc[h][t] = (f32x4){0.f, 0.f, 0.f, 0.f};
    const short* aptr0 = mtb + (size_t)(row0 + lr) * NPAD + lk;
    const short* aptr1 = aptr0 + (size_t)16 * NPAD;
    const short* bptr  = h2t + (size_t)lr * NPAD + lk;
    for (int k0 = kbeg; k0 < kend; k0 += 32) {
        bf16x8 a0 = *(const bf16x8*)(aptr0 + k0);
        bf16x8 a1 = *(const bf16x8*)(aptr1 + k0);
        #pragma unroll
        for (int t = 0; t < 16; ++t) {
            bf16x8 b = *(const bf16x8*)(bptr + (size_t)t * 16 * NPAD + k0);
            acc[0][t] = __builtin_amdgcn_mfma_f32_16x16x32_bf16(a0, b, acc[0][t], 0, 0, 0);
            acc[1][t] = __builtin_amdgcn_mfma_f32_16x16x32_bf16(a1, b, acc[1][t], 0, 0, 0);
        }
    }
    const int rbase = (lane >> 4) * 4;
    #pragma unroll
    for (int h = 0; h < 2; ++h) {
        int rb = row0 + h * 16 + rbase;
        #pragma unroll
        for (int t = 0; t < 16; ++t) {
            int col = t * 16 + lr;
            #pragma unroll
            for (int j = 0; j < 4; ++j)
                atomicAdd(&pcat[(size_t)(rb + j) * 256 + col], acc[h][t][j]);
        }
    }
}

// ---- layer-3 on pooled sums + mean + L2 normalize ----
__global__ __launch_bounds__(256) void k_final(const float* __restrict__ Pagg, const float* __restrict__ Ph2,
                                               const float* __restrict__ cntf,
                                               const float* __restrict__ Wr3, const float* __restrict__ br3,
                                               const float* __restrict__ Wo3, float* __restrict__ out) {
    __shared__ float sa[256], sh[256];
    __shared__ float wred[4];
    int g = blockIdx.x, t = threadIdx.x;
    sa[t] = Pagg[g * 256 + t];
    sh[t] = Ph2[g * 256 + t];
    __syncthreads();
    float c0 = 0.f, c1 = 0.f;
    #pragma unroll 4
    for (int k = 0; k < 256; ++k) {
        float a = sa[k], h = sh[k];
        c0 = fmaf(a, Wr3[k * 512 + t], c0);
        c0 = fmaf(h, Wo3[k * 512 + t], c0);
        c1 = fmaf(a, Wr3[k * 512 + t + 256], c1);
        c1 = fmaf(h, Wo3[k * 512 + t + 256], c1);
    }
    float cnt = cntf[g];
    float inv = 1.f / fmaxf(cnt, 1.f);
    float p0 = (c0 + cnt * br3[t]) * inv;
    float p1 = (c1 + cnt * br3[t + 256]) * inv;
    float ss = p0 * p0 + p1 * p1;
    for (int o = 32; o > 0; o >>= 1) ss += __shfl_down(ss, o);
    int lane = t & 63;
    if (lane == 0) wred[t >> 6] = ss;
    __syncthreads();
    float tot = wred[0] + wred[1] + wred[2] + wred[3];
    float inv2 = 1.f / fmaxf(sqrtf(tot), 1e-12f);
    out[g * 512 + t]       = p0 * inv2;
    out[g * 512 + t + 256] = p1 * inv2;
}

extern "C" void kernel_launch(void* const* d_in, const int* in_sizes, int n_in,
                              void* d_out, int out_size, void* d_ws, size_t ws_size,
                              hipStream_t stream) {
    const float* x   = (const float*)d_in[0];
    const int*   ei  = (const int*)d_in[1];
    const int*   bat = (const int*)d_in[2];
    const float* Wr1 = (const float*)d_in[3];
    const float* br1 = (const float*)d_in[4];
    const float* Wo1 = (const float*)d_in[5];
    const float* Wr2 = (const float*)d_in[6];
    const float* br2 = (const float*)d_in[7];
    const float* Wo2 = (const float*)d_in[8];
    const float* Wr3 = (const float*)d_in[9];
    const float* br3 = (const float*)d_in[10];
    const float* Wo3 = (const float*)d_in[11];
    const int* src = ei;
    const int* dst = ei + N_EDGES;

    char* ws = (char*)d_ws;
    float*          agg1 = (float*)(ws + OFF_AGG1);
    int*            deg  = (int*)(ws + OFF_DEG);
    int*            rowst= (int*)(ws + OFF_ROW);
    int*            cur  = (int*)(ws + OFF_CUR);
    int*            part = (int*)(ws + OFF_PART);
    int*            csr  = (int*)(ws + OFF_CSR);
    unsigned short* xcat = (unsigned short*)(ws + OFF_XCAT);
    float*          mt   = (float*)(ws + OFF_MT);
    unsigned short* mtb  = (unsigned short*)(ws + OFF_MTB);
    unsigned short* h2t  = (unsigned short*)(ws + OFF_H2T);
    unsigned short* wt   = (unsigned short*)(ws + OFF_WT);
    float*          pcat = (float*)(ws + OFF_PCAT);
    float*          cntf = (float*)(ws + OFF_CNT);

    hipMemsetAsync(agg1, 0, N_NODES * 4, stream);
    hipMemsetAsync(deg, 0, N_NODES * 4, stream);
    hipMemsetAsync(pcat, 0, 128 * 256 * 4 + 256, stream);   // Pcat + cnt

    k_edge1<<<(N_EDGES + 255) / 256, 256, 0, stream>>>(x, src, dst, agg1, deg);
    k_h1<<<(NPAD * 128) / 256, 256, 0, stream>>>(agg1, x, Wr1, Wo1, br1, xcat);
    k_scanA<<<98, 1024, 0, stream>>>(deg, rowst, part);
    k_scanB<<<1, 128, 0, stream>>>(part);
    k_scanC<<<(N_NODES + 255) / 256, 256, 0, stream>>>(rowst, cur, part);
    k_scatter<<<(N_EDGES + 255) / 256, 256, 0, stream>>>(src, dst, cur, csr);
    k_agg2<<<1024, 256, 0, stream>>>(agg1, x, rowst, deg, csr, Wr1, Wo1, br1, (unsigned int*)xcat);
    k_wt<<<256, 256, 0, stream>>>(Wr2, Wo2, wt);
    k_gemm<<<NPAD / 128, 256, 0, stream>>>((const short*)xcat, (const short*)wt, br2, h2t);

    // Xcat dead -> reuse its 51.25 MB as Mt (f32 counts) + Mtb (bf16 [M;B])
    hipMemsetAsync(ws + OFF_XCAT, 0, (size_t)NPAD * 256 * 2, stream);
    k_mbedges<<<(N_EDGES + 255) / 256, 256, 0, stream>>>(src, dst, bat, mt);
    k_mbnodes<<<(N_NODES + 255) / 256, 256, 0, stream>>>(bat, mtb, cntf);
    k_mconv<<<(64 * NPAD) / 2048, 256, 0, stream>>>(mt, mtb);
    k_pool_gemm<<<196, 256, 0, stream>>>((const short*)mtb, (const short*)h2t, pcat);
    k_final<<<NG, 256, 0, stream>>>(pcat, pcat + 64 * 256, cntf, Wr3, br3, Wo3, (float*)d_out);
}

// Round 5
// 484.404 us; speedup vs baseline: 3.0177x; 1.0995x over previous
//
#include <hip/hip_runtime.h>

#define N_NODES 100000
#define N_EDGES 800000
#define NG      64
#define NPAD    100096   // 782 * 128 = 391 * 256

// ---------------- workspace layout (bytes) ----------------
constexpr size_t OFF_AGG1 = 0;                              // N f32
constexpr size_t OFF_DEG  = OFF_AGG1 + 400128;              // N i32
constexpr size_t OFF_ROW  = OFF_DEG  + 400128;              // N i32
constexpr size_t OFF_CUR  = OFF_ROW  + 400128;              // N i32
constexpr size_t OFF_PART = OFF_CUR  + 400128;              // 128 i32
constexpr size_t OFF_CSR  = OFF_PART + 512;                 // E i32
constexpr size_t OFF_XCAT = OFF_CSR  + 3200000;             // NPAD*256 bf16 = 51,249,152 B
// after k_gemm, XCAT region is reused:
constexpr size_t OFF_MT   = OFF_XCAT;                       // 64*NPAD f32   = 25,624,576 B
constexpr size_t OFF_MTB  = OFF_XCAT + 25624576;            // 128*NPAD bf16 = 25,624,576 B
constexpr size_t OFF_H2T  = OFF_XCAT + (size_t)NPAD*256*2;  // 256*NPAD bf16 (transposed h2)
constexpr size_t OFF_WT   = OFF_H2T  + (size_t)NPAD*256*2;  // 256*256 bf16
constexpr size_t OFF_PCAT = OFF_WT   + 256*256*2;           // 128*256 f32
constexpr size_t OFF_CNT  = OFF_PCAT + 128*256*4;           // 64 f32

typedef __attribute__((ext_vector_type(8))) short bf16x8;
typedef __attribute__((ext_vector_type(8))) unsigned short u16x8;
typedef __attribute__((ext_vector_type(4))) unsigned short u16x4;
typedef __attribute__((ext_vector_type(4))) float f32x4;

__device__ __forceinline__ float bfu2f(unsigned short u) {
    return __uint_as_float(((unsigned)u) << 16);
}
__device__ __forceinline__ unsigned short f2bfu(float f) {
    unsigned u = __float_as_uint(f);
    unsigned r = (u + 0x7FFFu + ((u >> 16) & 1u)) >> 16;   // RNE
    return (unsigned short)r;
}

// ---- layer-1 scalar aggregation + degree histogram (one edge pass) ----
__global__ void k_edge1(const float* __restrict__ x, const int* __restrict__ src,
                        const int* __restrict__ dst, float* agg1, int* deg) {
    int e = blockIdx.x * 256 + threadIdx.x;
    if (e >= N_EDGES) return;
    int s = src[e], d = dst[e];
    atomicAdd(&agg1[d], x[s]);
    atomicAdd(&deg[d], 1);
}

// ---- h1 = relu(a*u + x*v + b) -> Xcat[:,128:256] (bf16) ----
__global__ void k_h1(const float* __restrict__ agg1, const float* __restrict__ x,
                     const float* __restrict__ Wr1, const float* __restrict__ Wo1,
                     const float* __restrict__ br1, unsigned short* __restrict__ xcat) {
    int gid = blockIdx.x * 256 + threadIdx.x;
    if (gid >= NPAD * 128) return;
    int i = gid >> 7, d = gid & 127;
    float v = 0.f;
    if (i < N_NODES)
        v = fmaxf(fmaf(agg1[i], Wr1[d], fmaf(x[i], Wo1[d], br1[d])), 0.f);
    xcat[(size_t)i * 256 + 128 + d] = f2bfu(v);
}

// ---- CSR build: block scan / partial scan / offsets / scatter ----
__global__ __launch_bounds__(1024) void k_scanA(const int* __restrict__ deg, int* rowst, int* part) {
    __shared__ int sm[1024];
    int t = threadIdx.x, i = blockIdx.x * 1024 + t;
    int v = (i < N_NODES) ? deg[i] : 0;
    sm[t] = v; __syncthreads();
    for (int o = 1; o < 1024; o <<= 1) {
        int y = (t >= o) ? sm[t - o] : 0;
        __syncthreads();
        sm[t] += y;
        __syncthreads();
    }
    if (i < N_NODES) rowst[i] = sm[t] - v;
    if (t == 1023) part[blockIdx.x] = sm[t];
}
__global__ void k_scanB(int* part) {   // 1 block, 128 threads; NB = 98
    __shared__ int sm[128];
    int t = threadIdx.x;
    int v = (t < 98) ? part[t] : 0;
    sm[t] = v; __syncthreads();
    for (int o = 1; o < 128; o <<= 1) {
        int y = (t >= o) ? sm[t - o] : 0;
        __syncthreads();
        sm[t] += y;
        __syncthreads();
    }
    if (t < 98) part[t] = sm[t] - v;
}
__global__ void k_scanC(int* rowst, int* cur, const int* __restrict__ part) {
    int i = blockIdx.x * 256 + threadIdx.x;
    if (i >= N_NODES) return;
    int r = rowst[i] + part[i >> 10];
    rowst[i] = r; cur[i] = r;
}
__global__ void k_scatter(const int* __restrict__ src, const int* __restrict__ dst,
                          int* cur, int* csr) {
    int e = blockIdx.x * 256 + threadIdx.x;
    if (e >= N_EDGES) return;
    int p = atomicAdd(&cur[dst[e]], 1);
    csr[p] = src[e];
}

// ---- agg2 via CSR: per-edge recompute h1[src] from 2 scalars, fp32 regs ----
__global__ __launch_bounds__(256) void k_agg2(const float* __restrict__ agg1, const float* __restrict__ x,
                                              const int* __restrict__ rowst, const int* __restrict__ deg,
                                              const int* __restrict__ csr,
                                              const float* __restrict__ Wr1, const float* __restrict__ Wo1,
                                              const float* __restrict__ br1, unsigned int* __restrict__ xcat_u32) {
    const int wave = threadIdx.x >> 6, lane = threadIdx.x & 63;
    const int d0 = 2 * lane, d1 = 2 * lane + 1;
    const float u0 = Wr1[d0], u1 = Wr1[d1];
    const float v0 = Wo1[d0], v1 = Wo1[d1];
    const float c0 = br1[d0], c1 = br1[d1];
    int wid = blockIdx.x * 4 + wave;
    int nw = gridDim.x * 4;
    for (int i = wid; i < NPAD; i += nw) {
        float a0 = 0.f, a1 = 0.f;
        if (i < N_NODES) {
            int dg = deg[i], st = rowst[i];
            for (int base = 0; base < dg; base += 64) {
                float av = 0.f, xv = 0.f;
                int e = base + lane;
                if (e < dg) { int s = csr[st + e]; av = agg1[s]; xv = x[s]; }
                int cnt = min(64, dg - base);
                for (int j = 0; j < cnt; ++j) {
                    float aj = __shfl(av, j);
                    float xj = __shfl(xv, j);
                    a0 += fmaxf(fmaf(aj, u0, fmaf(xj, v0, c0)), 0.f);
                    a1 += fmaxf(fmaf(aj, u1, fmaf(xj, v1, c1)), 0.f);
                }
            }
        }
        unsigned int w = (unsigned)f2bfu(a0) | ((unsigned)f2bfu(a1) << 16);
        xcat_u32[(size_t)i * 128 + lane] = w;
    }
}

// ---- Wcat^T (bf16): Wt[c][k] = (k<128 ? W_rel2[k][c] : W_root2[k-128][c]) ----
__global__ void k_wt(const float* __restrict__ Wr2, const float* __restrict__ Wo2,
                     unsigned short* __restrict__ Wt) {
    int gid = blockIdx.x * 256 + threadIdx.x;   // 65536
    int k = gid & 255, c = gid >> 8;
    float v = (k < 128) ? Wr2[k * 256 + c] : Wo2[(k - 128) * 256 + c];
    Wt[c * 256 + k] = f2bfu(v);
}

// ---- layer-2 GEMM: h2 = relu(Xcat @ Wcat + b2), bf16 MFMA; stores h2 TRANSPOSED ----
// 64x64 per wave (acc=64 regs), block = 2x2 waves = 128x128, grid (NPAD/128, 2)
__global__ __launch_bounds__(256) void k_gemm(const short* __restrict__ Xcat, const short* __restrict__ Wt,
                                              const float* __restrict__ b2, unsigned short* __restrict__ h2t) {
    const int wave = threadIdx.x >> 6, lane = threadIdx.x & 63;
    const int r0 = blockIdx.x * 128 + (wave >> 1) * 64;
    const int c0 = blockIdx.y * 128 + (wave & 1) * 64;
    const int lr = lane & 15;
    const int lk = (lane >> 4) << 3;          // 0,8,16,24
    f32x4 acc[4][4];
    #pragma unroll
    for (int m = 0; m < 4; ++m)
        #pragma unroll
        for (int t = 0; t < 4; ++t) acc[m][t] = (f32x4){0.f, 0.f, 0.f, 0.f};
    const short* ap = Xcat + (size_t)(r0 + lr) * 256 + lk;
    const short* bp = Wt   + (size_t)(c0 + lr) * 256 + lk;
    #pragma unroll
    for (int k0 = 0; k0 < 256; k0 += 32) {
        bf16x8 a[4], b[4];
        #pragma unroll
        for (int m = 0; m < 4; ++m) a[m] = *(const bf16x8*)(ap + m * 16 * 256 + k0);
        #pragma unroll
        for (int t = 0; t < 4; ++t) b[t] = *(const bf16x8*)(bp + t * 16 * 256 + k0);
        #pragma unroll
        for (int m = 0; m < 4; ++m)
            #pragma unroll
            for (int t = 0; t < 4; ++t)
                acc[m][t] = __builtin_amdgcn_mfma_f32_16x16x32_bf16(a[m], b[t], acc[m][t], 0, 0, 0);
    }
    const int rb = (lane >> 4) * 4;
    #pragma unroll
    for (int m = 0; m < 4; ++m) {
        int row = r0 + m * 16 + rb;
        #pragma unroll
        for (int t = 0; t < 4; ++t) {
            int col = c0 + t * 16 + lr;
            float bias = b2[col];
            u16x4 w;
            #pragma unroll
            for (int j = 0; j < 4; ++j)
                w[j] = f2bfu(fmaxf(acc[m][t][j] + bias, 0.f));
            *(u16x4*)(h2t + (size_t)col * NPAD + row) = w;   // transposed store, 8B/lane
        }
    }
}

// ---- count-matrix build: edges -> Mt (f32 atomics), rows 0..63 ----
__global__ void k_mbedges(const int* __restrict__ src, const int* __restrict__ dst,
                          const int* __restrict__ batch, float* __restrict__ mt) {
    int e = blockIdx.x * 256 + threadIdx.x;
    if (e >= N_EDGES) return;
    int g = batch[dst[e]];
    atomicAdd(&mt[(size_t)g * NPAD + src[e]], 1.f);
}

// ---- indicator rows 64..127 (bf16, direct store) + per-graph node counts ----
__global__ __launch_bounds__(256) void k_mbnodes(const int* __restrict__ batch,
                                                 unsigned short* __restrict__ mtb, float* cntf) {
    __shared__ float lc[NG];
    int t = threadIdx.x;
    if (t < NG) lc[t] = 0.f;
    __syncthreads();
    int i = blockIdx.x * 256 + t;
    if (i < N_NODES) {
        int g = batch[i];
        mtb[(size_t)(64 + g) * NPAD + i] = 0x3F80;   // bf16 1.0
        atomicAdd(&lc[g], 1.f);
    }
    __syncthreads();
    if (t < NG) atomicAdd(&cntf[t], lc[t]);
}

// ---- convert count rows f32 -> bf16 (rows 0..63 of Mtb) ----
__global__ void k_mconv(const float* __restrict__ mt, unsigned short* __restrict__ mtb) {
    size_t base = ((size_t)blockIdx.x * 256 + threadIdx.x) * 8;   // 64*NPAD total, exact
    f32x4 a = *(const f32x4*)(mt + base);
    f32x4 b = *(const f32x4*)(mt + base + 4);
    u16x8 w;
    #pragma unroll
    for (int j = 0; j < 4; ++j) { w[j] = f2bfu(a[j]); w[4 + j] = f2bfu(b[j]); }
    *(u16x8*)(mtb + base) = w;
}

// ---- pooling GEMM: Pcat[128][256] += Mtb[128][K-slice] @ h2t^T, MFMA ----
// 64x64 per wave, block = (M 2x64) x (N 2x64), grid (196 K-slices of 512, 2 col-halves)
__global__ __launch_bounds__(256) void k_pool_gemm(const short* __restrict__ mtb,
                                                   const short* __restrict__ h2t,
                                                   float* __restrict__ pcat) {
    const int wave = threadIdx.x >> 6, lane = threadIdx.x & 63;
    const int m0 = (wave >> 1) * 64;
    const int c0 = blockIdx.y * 128 + (wave & 1) * 64;
    const int lr = lane & 15;
    const int lk = (lane >> 4) << 3;
    const int kbeg = blockIdx.x * 512;
    const int kend = min(kbeg + 512, NPAD);
    f32x4 acc[4][4];
    #pragma unroll
    for (int m = 0; m < 4; ++m)
        #pragma unroll
        for (int t = 0; t < 4; ++t) acc[m][t] = (f32x4){0.f, 0.f, 0.f, 0.f};
    const short* ap = mtb + (size_t)(m0 + lr) * NPAD + lk;
    const short* bp = h2t + (size_t)(c0 + lr) * NPAD + lk;
    for (int k0 = kbeg; k0 < kend; k0 += 32) {
        bf16x8 a[4], b[4];
        #pragma unroll
        for (int m = 0; m < 4; ++m) a[m] = *(const bf16x8*)(ap + (size_t)m * 16 * NPAD + k0);
        #pragma unroll
        for (int t = 0; t < 4; ++t) b[t] = *(const bf16x8*)(bp + (size_t)t * 16 * NPAD + k0);
        #pragma unroll
        for (int m = 0; m < 4; ++m)
            #pragma unroll
            for (int t = 0; t < 4; ++t)
                acc[m][t] = __builtin_amdgcn_mfma_f32_16x16x32_bf16(a[m], b[t], acc[m][t], 0, 0, 0);
    }
    const int rb = (lane >> 4) * 4;
    #pragma unroll
    for (int m = 0; m < 4; ++m) {
        int row = m0 + m * 16 + rb;
        #pragma unroll
        for (int t = 0; t < 4; ++t) {
            int col = c0 + t * 16 + lr;
            #pragma unroll
            for (int j = 0; j < 4; ++j)
                atomicAdd(&pcat[(size_t)(row + j) * 256 + col], acc[m][t][j]);
        }
    }
}

// ---- layer-3 on pooled sums + mean + L2 normalize ----
__global__ __launch_bounds__(256) void k_final(const float* __restrict__ Pagg, const float* __restrict__ Ph2,
                                               const float* __restrict__ cntf,
                                               const float* __restrict__ Wr3, const float* __restrict__ br3,
                                               const float* __restrict__ Wo3, float* __restrict__ out) {
    __shared__ float sa[256], sh[256];
    __shared__ float wred[4];
    int g = blockIdx.x, t = threadIdx.x;
    sa[t] = Pagg[g * 256 + t];
    sh[t] = Ph2[g * 256 + t];
    __syncthreads();
    float c0 = 0.f, c1 = 0.f;
    #pragma unroll 4
    for (int k = 0; k < 256; ++k) {
        float a = sa[k], h = sh[k];
        c0 = fmaf(a, Wr3[k * 512 + t], c0);
        c0 = fmaf(h, Wo3[k * 512 + t], c0);
        c1 = fmaf(a, Wr3[k * 512 + t + 256], c1);
        c1 = fmaf(h, Wo3[k * 512 + t + 256], c1);
    }
    float cnt = cntf[g];
    float inv = 1.f / fmaxf(cnt, 1.f);
    float p0 = (c0 + cnt * br3[t]) * inv;
    float p1 = (c1 + cnt * br3[t + 256]) * inv;
    float ss = p0 * p0 + p1 * p1;
    for (int o = 32; o > 0; o >>= 1) ss += __shfl_down(ss, o);
    int lane = t & 63;
    if (lane == 0) wred[t >> 6] = ss;
    __syncthreads();
    float tot = wred[0] + wred[1] + wred[2] + wred[3];
    float inv2 = 1.f / fmaxf(sqrtf(tot), 1e-12f);
    out[g * 512 + t]       = p0 * inv2;
    out[g * 512 + t + 256] = p1 * inv2;
}

extern "C" void kernel_launch(void* const* d_in, const int* in_sizes, int n_in,
                              void* d_out, int out_size, void* d_ws, size_t ws_size,
                              hipStream_t stream) {
    const float* x   = (const float*)d_in[0];
    const int*   ei  = (const int*)d_in[1];
    const int*   bat = (const int*)d_in[2];
    const float* Wr1 = (const float*)d_in[3];
    const float* br1 = (const float*)d_in[4];
    const float* Wo1 = (const float*)d_in[5];
    const float* Wr2 = (const float*)d_in[6];
    const float* br2 = (const float*)d_in[7];
    const float* Wo2 = (const float*)d_in[8];
    const float* Wr3 = (const float*)d_in[9];
    const float* br3 = (const float*)d_in[10];
    const float* Wo3 = (const float*)d_in[11];
    const int* src = ei;
    const int* dst = ei + N_EDGES;

    char* ws = (char*)d_ws;
    float*          agg1 = (float*)(ws + OFF_AGG1);
    int*            deg  = (int*)(ws + OFF_DEG);
    int*            rowst= (int*)(ws + OFF_ROW);
    int*            cur  = (int*)(ws + OFF_CUR);
    int*            part = (int*)(ws + OFF_PART);
    int*            csr  = (int*)(ws + OFF_CSR);
    unsigned short* xcat = (unsigned short*)(ws + OFF_XCAT);
    float*          mt   = (float*)(ws + OFF_MT);
    unsigned short* mtb  = (unsigned short*)(ws + OFF_MTB);
    unsigned short* h2t  = (unsigned short*)(ws + OFF_H2T);
    unsigned short* wt   = (unsigned short*)(ws + OFF_WT);
    float*          pcat = (float*)(ws + OFF_PCAT);
    float*          cntf = (float*)(ws + OFF_CNT);

    hipMemsetAsync(agg1, 0, N_NODES * 4, stream);
    hipMemsetAsync(deg, 0, N_NODES * 4, stream);
    hipMemsetAsync(pcat, 0, 128 * 256 * 4 + 256, stream);   // Pcat + cnt

    k_edge1<<<(N_EDGES + 255) / 256, 256, 0, stream>>>(x, src, dst, agg1, deg);
    k_h1<<<(NPAD * 128) / 256, 256, 0, stream>>>(agg1, x, Wr1, Wo1, br1, xcat);
    k_scanA<<<98, 1024, 0, stream>>>(deg, rowst, part);
    k_scanB<<<1, 128, 0, stream>>>(part);
    k_scanC<<<(N_NODES + 255) / 256, 256, 0, stream>>>(rowst, cur, part);
    k_scatter<<<(N_EDGES + 255) / 256, 256, 0, stream>>>(src, dst, cur, csr);
    k_agg2<<<1024, 256, 0, stream>>>(agg1, x, rowst, deg, csr, Wr1, Wo1, br1, (unsigned int*)xcat);
    k_wt<<<256, 256, 0, stream>>>(Wr2, Wo2, wt);
    k_gemm<<<dim3(NPAD / 128, 2), 256, 0, stream>>>((const short*)xcat, (const short*)wt, br2, h2t);

    // Xcat dead -> reuse its 51.25 MB as Mt (f32 counts) + Mtb (bf16 [M;B])
    hipMemsetAsync(ws + OFF_XCAT, 0, (size_t)NPAD * 256 * 2, stream);
    k_mbedges<<<(N_EDGES + 255) / 256, 256, 0, stream>>>(src, dst, bat, mt);
    k_mbnodes<<<(N_NODES + 255) / 256, 256, 0, stream>>>(bat, mtb, cntf);
    k_mconv<<<(64 * NPAD) / 2048, 256, 0, stream>>>(mt, mtb);
    k_pool_gemm<<<dim3(196, 2), 256, 0, stream>>>((const short*)mtb, (const short*)h2t, pcat);
    k_final<<<NG, 256, 0, stream>>>(pcat, pcat + 64 * 256, cntf, Wr3, br3, Wo3, (float*)d_out);
}

// Round 6
// 453.710 us; speedup vs baseline: 3.2218x; 1.0677x over previous
//
#include <hip/hip_runtime.h>

#define N_NODES 100000
#define N_EDGES 800000
#define NG      64
#define NPAD    100096   // 782 * 128 = 391 * 256

// ---------------- workspace layout (bytes) ----------------
// packed agg1: u64 per node = {deg:20 bits (hi), deg*2^24 + sum(x*2^20):44 bits (lo)}
constexpr size_t OFF_AGG1P = 0;                              // N u64 (800256)
constexpr size_t OFF_ROW  = OFF_AGG1P + 800256;              // N i32
constexpr size_t OFF_CUR  = OFF_ROW  + 400128;               // N i32
constexpr size_t OFF_PART = OFF_CUR  + 400128;               // 128 i32
constexpr size_t OFF_CSR  = OFF_PART + 512;                  // E i32
constexpr size_t OFF_XCAT = OFF_CSR  + 3200000;              // NPAD*256 bf16 = 51,249,152 B
// after k_gemm, XCAT region is reused:
constexpr size_t OFF_MT   = OFF_XCAT;                        // 64*NPAD f32   = 25,624,576 B
constexpr size_t OFF_MTB  = OFF_XCAT + 25624576;             // 128*NPAD bf16 = 25,624,576 B
constexpr size_t OFF_H2T  = OFF_XCAT + (size_t)NPAD*256*2;   // 256*NPAD bf16 (transposed h2)
constexpr size_t OFF_WT   = OFF_H2T  + (size_t)NPAD*256*2;   // 256*256 bf16
constexpr size_t OFF_PCAT = OFF_WT   + 256*256*2;            // 128*256 f32
constexpr size_t OFF_CNT  = OFF_PCAT + 128*256*4;            // 64 f32

typedef __attribute__((ext_vector_type(8))) short bf16x8;
typedef __attribute__((ext_vector_type(8))) unsigned short u16x8;
typedef __attribute__((ext_vector_type(4))) unsigned short u16x4;
typedef __attribute__((ext_vector_type(4))) float f32x4;

__device__ __forceinline__ float bfu2f(unsigned short u) {
    return __uint_as_float(((unsigned)u) << 16);
}
__device__ __forceinline__ unsigned short f2bfu(float f) {
    unsigned u = __float_as_uint(f);
    unsigned r = (u + 0x7FFFu + ((u >> 16) & 1u)) >> 16;   // RNE
    return (unsigned short)r;
}

#define PK_MASK ((1LL << 44) - 1)
__device__ __forceinline__ float pk_agg(long long v) {
    long long dg = v >> 44;
    return (float)((v & PK_MASK) - (dg << 24)) * (1.f / 1048576.f);
}
__device__ __forceinline__ int pk_deg(long long v) { return (int)(v >> 44); }

// ---- layer-1: ONE packed u64 atomic per edge {deg, fixed-point sum} ----
__global__ void k_edge1(const float* __restrict__ x, const int* __restrict__ src,
                        const int* __restrict__ dst, unsigned long long* __restrict__ agg1p) {
    int e = blockIdx.x * 256 + threadIdx.x;
    if (e >= N_EDGES) return;
    int s = src[e], d = dst[e];
    long long fixed = (long long)lrintf(x[s] * 1048576.f);
    unsigned long long add = (1ULL << 44) + (unsigned long long)(fixed + (1LL << 24));
    atomicAdd(&agg1p[d], add);
}

// ---- h1 = relu(a*u + x*v + b) -> Xcat[:,128:256] (bf16) ----
__global__ void k_h1(const long long* __restrict__ agg1p, const float* __restrict__ x,
                     const float* __restrict__ Wr1, const float* __restrict__ Wo1,
                     const float* __restrict__ br1, unsigned short* __restrict__ xcat) {
    int gid = blockIdx.x * 256 + threadIdx.x;
    if (gid >= NPAD * 128) return;
    int i = gid >> 7, d = gid & 127;
    float v = 0.f;
    if (i < N_NODES) {
        float a = pk_agg(agg1p[i]);
        v = fmaxf(fmaf(a, Wr1[d], fmaf(x[i], Wo1[d], br1[d])), 0.f);
    }
    xcat[(size_t)i * 256 + 128 + d] = f2bfu(v);
}

// ---- CSR build: block scan / partial scan / offsets / scatter ----
__global__ __launch_bounds__(1024) void k_scanA(const long long* __restrict__ agg1p, int* rowst, int* part) {
    __shared__ int sm[1024];
    int t = threadIdx.x, i = blockIdx.x * 1024 + t;
    int v = (i < N_NODES) ? pk_deg(agg1p[i]) : 0;
    sm[t] = v; __syncthreads();
    for (int o = 1; o < 1024; o <<= 1) {
        int y = (t >= o) ? sm[t - o] : 0;
        __syncthreads();
        sm[t] += y;
        __syncthreads();
    }
    if (i < N_NODES) rowst[i] = sm[t] - v;
    if (t == 1023) part[blockIdx.x] = sm[t];
}
__global__ void k_scanB(int* part) {   // 1 block, 128 threads; NB = 98
    __shared__ int sm[128];
    int t = threadIdx.x;
    int v = (t < 98) ? part[t] : 0;
    sm[t] = v; __syncthreads();
    for (int o = 1; o < 128; o <<= 1) {
        int y = (t >= o) ? sm[t - o] : 0;
        __syncthreads();
        sm[t] += y;
        __syncthreads();
    }
    if (t < 98) part[t] = sm[t] - v;
}
__global__ void k_scanC(int* rowst, int* cur, const int* __restrict__ part) {
    int i = blockIdx.x * 256 + threadIdx.x;
    if (i >= N_NODES) return;
    int r = rowst[i] + part[i >> 10];
    rowst[i] = r; cur[i] = r;
}
__global__ void k_scatter(const int* __restrict__ src, const int* __restrict__ dst,
                          int* cur, int* csr) {
    int e = blockIdx.x * 256 + threadIdx.x;
    if (e >= N_EDGES) return;
    int p = atomicAdd(&cur[dst[e]], 1);
    csr[p] = src[e];
}

// ---- agg2 via CSR: per-edge recompute h1[src] from 2 scalars, fp32 regs ----
__global__ __launch_bounds__(256) void k_agg2(const long long* __restrict__ agg1p, const float* __restrict__ x,
                                              const int* __restrict__ rowst,
                                              const int* __restrict__ csr,
                                              const float* __restrict__ Wr1, const float* __restrict__ Wo1,
                                              const float* __restrict__ br1, unsigned int* __restrict__ xcat_u32) {
    const int wave = threadIdx.x >> 6, lane = threadIdx.x & 63;
    const int d0 = 2 * lane, d1 = 2 * lane + 1;
    const float u0 = Wr1[d0], u1 = Wr1[d1];
    const float v0 = Wo1[d0], v1 = Wo1[d1];
    const float c0 = br1[d0], c1 = br1[d1];
    int wid = blockIdx.x * 4 + wave;
    int nw = gridDim.x * 4;
    for (int i = wid; i < NPAD; i += nw) {
        float a0 = 0.f, a1 = 0.f;
        if (i < N_NODES) {
            long long pv = agg1p[i];
            int dg = pk_deg(pv), st = rowst[i];
            for (int base = 0; base < dg; base += 64) {
                float av = 0.f, xv = 0.f;
                int e = base + lane;
                if (e < dg) { int s = csr[st + e]; av = pk_agg(agg1p[s]); xv = x[s]; }
                int cnt = min(64, dg - base);
                for (int j = 0; j < cnt; ++j) {
                    float aj = __shfl(av, j);
                    float xj = __shfl(xv, j);
                    a0 += fmaxf(fmaf(aj, u0, fmaf(xj, v0, c0)), 0.f);
                    a1 += fmaxf(fmaf(aj, u1, fmaf(xj, v1, c1)), 0.f);
                }
            }
        }
        unsigned int w = (unsigned)f2bfu(a0) | ((unsigned)f2bfu(a1) << 16);
        xcat_u32[(size_t)i * 128 + lane] = w;
    }
}

// ---- Wcat^T (bf16): Wt[c][k] = (k<128 ? W_rel2[k][c] : W_root2[k-128][c]) ----
__global__ void k_wt(const float* __restrict__ Wr2, const float* __restrict__ Wo2,
                     unsigned short* __restrict__ Wt) {
    int gid = blockIdx.x * 256 + threadIdx.x;   // 65536
    int k = gid & 255, c = gid >> 8;
    float v = (k < 128) ? Wr2[k * 256 + c] : Wo2[(k - 128) * 256 + c];
    Wt[c * 256 + k] = f2bfu(v);
}

// ---- layer-2 GEMM: h2 = relu(Xcat @ Wcat + b2), bf16 MFMA; stores h2 TRANSPOSED ----
// 64x64 per wave (acc=64 regs), block = 2x2 waves = 128x128, grid (NPAD/128, 2)
__global__ __launch_bounds__(256) void k_gemm(const short* __restrict__ Xcat, const short* __restrict__ Wt,
                                              const float* __restrict__ b2, unsigned short* __restrict__ h2t) {
    const int wave = threadIdx.x >> 6, lane = threadIdx.x & 63;
    const int r0 = blockIdx.x * 128 + (wave >> 1) * 64;
    const int c0 = blockIdx.y * 128 + (wave & 1) * 64;
    const int lr = lane & 15;
    const int lk = (lane >> 4) << 3;          // 0,8,16,24
    f32x4 acc[4][4];
    #pragma unroll
    for (int m = 0; m < 4; ++m)
        #pragma unroll
        for (int t = 0; t < 4; ++t) acc[m][t] = (f32x4){0.f, 0.f, 0.f, 0.f};
    const short* ap = Xcat + (size_t)(r0 + lr) * 256 + lk;
    const short* bp = Wt   + (size_t)(c0 + lr) * 256 + lk;
    #pragma unroll
    for (int k0 = 0; k0 < 256; k0 += 32) {
        bf16x8 a[4], b[4];
        #pragma unroll
        for (int m = 0; m < 4; ++m) a[m] = *(const bf16x8*)(ap + m * 16 * 256 + k0);
        #pragma unroll
        for (int t = 0; t < 4; ++t) b[t] = *(const bf16x8*)(bp + t * 16 * 256 + k0);
        #pragma unroll
        for (int m = 0; m < 4; ++m)
            #pragma unroll
            for (int t = 0; t < 4; ++t)
                acc[m][t] = __builtin_amdgcn_mfma_f32_16x16x32_bf16(a[m], b[t], acc[m][t], 0, 0, 0);
    }
    const int rb = (lane >> 4) * 4;
    #pragma unroll
    for (int m = 0; m < 4; ++m) {
        int row = r0 + m * 16 + rb;
        #pragma unroll
        for (int t = 0; t < 4; ++t) {
            int col = c0 + t * 16 + lr;
            float bias = b2[col];
            u16x4 w;
            #pragma unroll
            for (int j = 0; j < 4; ++j)
                w[j] = f2bfu(fmaxf(acc[m][t][j] + bias, 0.f));
            *(u16x4*)(h2t + (size_t)col * NPAD + row) = w;   // transposed store, 8B/lane
        }
    }
}

// ---- count-matrix build: edges -> Mt (f32 atomics), rows 0..63 ----
__global__ void k_mbedges(const int* __restrict__ src, const int* __restrict__ dst,
                          const int* __restrict__ batch, float* __restrict__ mt) {
    int e = blockIdx.x * 256 + threadIdx.x;
    if (e >= N_EDGES) return;
    int g = batch[dst[e]];
    atomicAdd(&mt[(size_t)g * NPAD + src[e]], 1.f);
}

// ---- indicator rows 64..127 (bf16, direct store) + per-graph node counts ----
__global__ __launch_bounds__(256) void k_mbnodes(const int* __restrict__ batch,
                                                 unsigned short* __restrict__ mtb, float* cntf) {
    __shared__ float lc[NG];
    int t = threadIdx.x;
    if (t < NG) lc[t] = 0.f;
    __syncthreads();
    int i = blockIdx.x * 256 + t;
    if (i < N_NODES) {
        int g = batch[i];
        mtb[(size_t)(64 + g) * NPAD + i] = 0x3F80;   // bf16 1.0
        atomicAdd(&lc[g], 1.f);
    }
    __syncthreads();
    if (t < NG) atomicAdd(&cntf[t], lc[t]);
}

// ---- convert count rows f32 -> bf16 (rows 0..63 of Mtb; writes ALL elements) ----
__global__ void k_mconv(const float* __restrict__ mt, unsigned short* __restrict__ mtb) {
    size_t base = ((size_t)blockIdx.x * 256 + threadIdx.x) * 8;   // 64*NPAD total, exact
    f32x4 a = *(const f32x4*)(mt + base);
    f32x4 b = *(const f32x4*)(mt + base + 4);
    u16x8 w;
    #pragma unroll
    for (int j = 0; j < 4; ++j) { w[j] = f2bfu(a[j]); w[4 + j] = f2bfu(b[j]); }
    *(u16x8*)(mtb + base) = w;
}

// ---- pooling GEMM: Pcat[128][256] += Mtb[128][K-slice] @ h2t^T, MFMA ----
// 64x64 per wave, block = (M 2x64) x (N 2x64), grid (196 K-slices of 512, 2 col-halves)
__global__ __launch_bounds__(256) void k_pool_gemm(const short* __restrict__ mtb,
                                                   const short* __restrict__ h2t,
                                                   float* __restrict__ pcat) {
    const int wave = threadIdx.x >> 6, lane = threadIdx.x & 63;
    const int m0 = (wave >> 1) * 64;
    const int c0 = blockIdx.y * 128 + (wave & 1) * 64;
    const int lr = lane & 15;
    const int lk = (lane >> 4) << 3;
    const int kbeg = blockIdx.x * 512;
    const int kend = min(kbeg + 512, NPAD);
    f32x4 acc[4][4];
    #pragma unroll
    for (int m = 0; m < 4; ++m)
        #pragma unroll
        for (int t = 0; t < 4; ++t) acc[m][t] = (f32x4){0.f, 0.f, 0.f, 0.f};
    const short* ap = mtb + (size_t)(m0 + lr) * NPAD + lk;
    const short* bp = h2t + (size_t)(c0 + lr) * NPAD + lk;
    for (int k0 = kbeg; k0 < kend; k0 += 32) {
        bf16x8 a[4], b[4];
        #pragma unroll
        for (int m = 0; m < 4; ++m) a[m] = *(const bf16x8*)(ap + (size_t)m * 16 * NPAD + k0);
        #pragma unroll
        for (int t = 0; t < 4; ++t) b[t] = *(const bf16x8*)(bp + (size_t)t * 16 * NPAD + k0);
        #pragma unroll
        for (int m = 0; m < 4; ++m)
            #pragma unroll
            for (int t = 0; t < 4; ++t)
                acc[m][t] = __builtin_amdgcn_mfma_f32_16x16x32_bf16(a[m], b[t], acc[m][t], 0, 0, 0);
    }
    const int rb = (lane >> 4) * 4;
    #pragma unroll
    for (int m = 0; m < 4; ++m) {
        int row = m0 + m * 16 + rb;
        #pragma unroll
        for (int t = 0; t < 4; ++t) {
            int col = c0 + t * 16 + lr;
            #pragma unroll
            for (int j = 0; j < 4; ++j)
                atomicAdd(&pcat[(size_t)(row + j) * 256 + col], acc[m][t][j]);
        }
    }
}

// ---- layer-3 on pooled sums + mean + L2 normalize ----
__global__ __launch_bounds__(256) void k_final(const float* __restrict__ Pagg, const float* __restrict__ Ph2,
                                               const float* __restrict__ cntf,
                                               const float* __restrict__ Wr3, const float* __restrict__ br3,
                                               const float* __restrict__ Wo3, float* __restrict__ out) {
    __shared__ float sa[256], sh[256];
    __shared__ float wred[4];
    int g = blockIdx.x, t = threadIdx.x;
    sa[t] = Pagg[g * 256 + t];
    sh[t] = Ph2[g * 256 + t];
    __syncthreads();
    float c0 = 0.f, c1 = 0.f;
    #pragma unroll 4
    for (int k = 0; k < 256; ++k) {
        float a = sa[k], h = sh[k];
        c0 = fmaf(a, Wr3[k * 512 + t], c0);
        c0 = fmaf(h, Wo3[k * 512 + t], c0);
        c1 = fmaf(a, Wr3[k * 512 + t + 256], c1);
        c1 = fmaf(h, Wo3[k * 512 + t + 256], c1);
    }
    float cnt = cntf[g];
    float inv = 1.f / fmaxf(cnt, 1.f);
    float p0 = (c0 + cnt * br3[t]) * inv;
    float p1 = (c1 + cnt * br3[t + 256]) * inv;
    float ss = p0 * p0 + p1 * p1;
    for (int o = 32; o > 0; o >>= 1) ss += __shfl_down(ss, o);
    int lane = t & 63;
    if (lane == 0) wred[t >> 6] = ss;
    __syncthreads();
    float tot = wred[0] + wred[1] + wred[2] + wred[3];
    float inv2 = 1.f / fmaxf(sqrtf(tot), 1e-12f);
    out[g * 512 + t]       = p0 * inv2;
    out[g * 512 + t + 256] = p1 * inv2;
}

extern "C" void kernel_launch(void* const* d_in, const int* in_sizes, int n_in,
                              void* d_out, int out_size, void* d_ws, size_t ws_size,
                              hipStream_t stream) {
    const float* x   = (const float*)d_in[0];
    const int*   ei  = (const int*)d_in[1];
    const int*   bat = (const int*)d_in[2];
    const float* Wr1 = (const float*)d_in[3];
    const float* br1 = (const float*)d_in[4];
    const float* Wo1 = (const float*)d_in[5];
    const float* Wr2 = (const float*)d_in[6];
    const float* br2 = (const float*)d_in[7];
    const float* Wo2 = (const float*)d_in[8];
    const float* Wr3 = (const float*)d_in[9];
    const float* br3 = (const float*)d_in[10];
    const float* Wo3 = (const float*)d_in[11];
    const int* src = ei;
    const int* dst = ei + N_EDGES;

    char* ws = (char*)d_ws;
    unsigned long long* agg1p = (unsigned long long*)(ws + OFF_AGG1P);
    int*            rowst= (int*)(ws + OFF_ROW);
    int*            cur  = (int*)(ws + OFF_CUR);
    int*            part = (int*)(ws + OFF_PART);
    int*            csr  = (int*)(ws + OFF_CSR);
    unsigned short* xcat = (unsigned short*)(ws + OFF_XCAT);
    float*          mt   = (float*)(ws + OFF_MT);
    unsigned short* mtb  = (unsigned short*)(ws + OFF_MTB);
    unsigned short* h2t  = (unsigned short*)(ws + OFF_H2T);
    unsigned short* wt   = (unsigned short*)(ws + OFF_WT);
    float*          pcat = (float*)(ws + OFF_PCAT);
    float*          cntf = (float*)(ws + OFF_CNT);

    hipMemsetAsync(agg1p, 0, (size_t)N_NODES * 8, stream);
    hipMemsetAsync(pcat, 0, 128 * 256 * 4 + 256, stream);   // Pcat + cnt

    k_edge1<<<(N_EDGES + 255) / 256, 256, 0, stream>>>(x, src, dst, agg1p);
    k_h1<<<(NPAD * 128) / 256, 256, 0, stream>>>((const long long*)agg1p, x, Wr1, Wo1, br1, xcat);
    k_scanA<<<98, 1024, 0, stream>>>((const long long*)agg1p, rowst, part);
    k_scanB<<<1, 128, 0, stream>>>(part);
    k_scanC<<<(N_NODES + 255) / 256, 256, 0, stream>>>(rowst, cur, part);
    k_scatter<<<(N_EDGES + 255) / 256, 256, 0, stream>>>(src, dst, cur, csr);
    k_agg2<<<1024, 256, 0, stream>>>((const long long*)agg1p, x, rowst, csr, Wr1, Wo1, br1, (unsigned int*)xcat);
    k_wt<<<256, 256, 0, stream>>>(Wr2, Wo2, wt);
    k_gemm<<<dim3(NPAD / 128, 2), 256, 0, stream>>>((const short*)xcat, (const short*)wt, br2, h2t);

    // Xcat dead -> reuse its 51.25 MB as Mt (f32 counts) + Mtb (bf16 [M;B])
    // zero only what's needed: mt (atomic base) + indicator rows of mtb
    hipMemsetAsync(ws + OFF_MT, 0, (size_t)64 * NPAD * 4, stream);
    hipMemsetAsync(ws + OFF_MTB + (size_t)64 * NPAD * 2, 0, (size_t)64 * NPAD * 2, stream);
    k_mbedges<<<(N_EDGES + 255) / 256, 256, 0, stream>>>(src, dst, bat, mt);
    k_mbnodes<<<(N_NODES + 255) / 256, 256, 0, stream>>>(bat, mtb, cntf);
    k_mconv<<<(64 * NPAD) / 2048, 256, 0, stream>>>(mt, mtb);
    k_pool_gemm<<<dim3(196, 2), 256, 0, stream>>>((const short*)mtb, (const short*)h2t, pcat);
    k_final<<<NG, 256, 0, stream>>>(pcat, pcat + 64 * 256, cntf, Wr3, br3, Wo3, (float*)d_out);
}

// Round 10
// 428.396 us; speedup vs baseline: 3.4122x; 1.0591x over previous
//
#include <hip/hip_runtime.h>

#define N_NODES 100000
#define N_EDGES 800000
#define NG      64
#define NPAD    100096   // 782 * 128 = 391 * 256

// ---------------- workspace layout (bytes) ----------------
// packed agg1: u64 per node = {deg:20 bits (hi), deg*2^24 + sum(x*2^20):44 bits (lo)}
constexpr size_t OFF_AGG1P = 0;                              // N u64 (800256)
constexpr size_t OFF_ROW  = OFF_AGG1P + 800256;              // N i32
constexpr size_t OFF_CUR  = OFF_ROW  + 400128;               // N i32
constexpr size_t OFF_PART = OFF_CUR  + 400128;               // 128 i32
constexpr size_t OFF_CSR  = OFF_PART + 512;                  // E i32
constexpr size_t OFF_XCAT = OFF_CSR  + 3200000;              // NPAD*256 bf16 = 51,249,152 B
// after k_gemm, XCAT region is reused:
constexpr size_t OFF_MT   = OFF_XCAT;                        // 64*NPAD f32   = 25,624,576 B
constexpr size_t OFF_MTB  = OFF_XCAT + 25624576;             // 128*NPAD bf16 = 25,624,576 B
constexpr size_t OFF_H2T  = OFF_XCAT + (size_t)NPAD*256*2;   // 256*NPAD bf16 (transposed h2)
constexpr size_t OFF_WT   = OFF_H2T  + (size_t)NPAD*256*2;   // 256*256 bf16
constexpr size_t OFF_PCAT = OFF_WT   + 256*256*2;            // 128*256 f32
constexpr size_t OFF_CNT  = OFF_PCAT + 128*256*4;            // 64 f32

typedef __attribute__((ext_vector_type(8))) short bf16x8;
typedef __attribute__((ext_vector_type(8))) unsigned short u16x8;
typedef __attribute__((ext_vector_type(4))) unsigned short u16x4;
typedef __attribute__((ext_vector_type(4))) float f32x4;

__device__ __forceinline__ float bfu2f(unsigned short u) {
    return __uint_as_float(((unsigned)u) << 16);
}
__device__ __forceinline__ unsigned short f2bfu(float f) {
    unsigned u = __float_as_uint(f);
    unsigned r = (u + 0x7FFFu + ((u >> 16) & 1u)) >> 16;   // RNE
    return (unsigned short)r;
}

__device__ __forceinline__ void load_lds16(const void* g, void* l) {
    __builtin_amdgcn_global_load_lds(
        (const __attribute__((address_space(1))) unsigned int*)g,
        (__attribute__((address_space(3))) unsigned int*)l, 16, 0, 0);
}

#define PK_MASK ((1LL << 44) - 1)
__device__ __forceinline__ float pk_agg(long long v) {
    long long dg = v >> 44;
    return (float)((v & PK_MASK) - (dg << 24)) * (1.f / 1048576.f);
}
__device__ __forceinline__ int pk_deg(long long v) { return (int)(v >> 44); }

// ---- layer-1: ONE packed u64 atomic per edge {deg, fixed-point sum} ----
__global__ void k_edge1(const float* __restrict__ x, const int* __restrict__ src,
                        const int* __restrict__ dst, unsigned long long* __restrict__ agg1p) {
    int e = blockIdx.x * 256 + threadIdx.x;
    if (e >= N_EDGES) return;
    int s = src[e], d = dst[e];
    long long fixed = (long long)lrintf(x[s] * 1048576.f);
    unsigned long long add = (1ULL << 44) + (unsigned long long)(fixed + (1LL << 24));
    atomicAdd(&agg1p[d], add);
}

// ---- h1 = relu(a*u + x*v + b) -> Xcat[:,128:256] (bf16) ----
__global__ void k_h1(const long long* __restrict__ agg1p, const float* __restrict__ x,
                     const float* __restrict__ Wr1, const float* __restrict__ Wo1,
                     const float* __restrict__ br1, unsigned short* __restrict__ xcat) {
    int gid = blockIdx.x * 256 + threadIdx.x;
    if (gid >= NPAD * 128) return;
    int i = gid >> 7, d = gid & 127;
    float v = 0.f;
    if (i < N_NODES) {
        float a = pk_agg(agg1p[i]);
        v = fmaxf(fmaf(a, Wr1[d], fmaf(x[i], Wo1[d], br1[d])), 0.f);
    }
    xcat[(size_t)i * 256 + 128 + d] = f2bfu(v);
}

// ---- CSR build: block scan / partial scan / offsets / scatter ----
__global__ __launch_bounds__(1024) void k_scanA(const long long* __restrict__ agg1p, int* rowst, int* part) {
    __shared__ int sm[1024];
    int t = threadIdx.x, i = blockIdx.x * 1024 + t;
    int v = (i < N_NODES) ? pk_deg(agg1p[i]) : 0;
    sm[t] = v; __syncthreads();
    for (int o = 1; o < 1024; o <<= 1) {
        int y = (t >= o) ? sm[t - o] : 0;
        __syncthreads();
        sm[t] += y;
        __syncthreads();
    }
    if (i < N_NODES) rowst[i] = sm[t] - v;
    if (t == 1023) part[blockIdx.x] = sm[t];
}
__global__ void k_scanB(int* part) {   // 1 block, 128 threads; NB = 98
    __shared__ int sm[128];
    int t = threadIdx.x;
    int v = (t < 98) ? part[t] : 0;
    sm[t] = v; __syncthreads();
    for (int o = 1; o < 128; o <<= 1) {
        int y = (t >= o) ? sm[t - o] : 0;
        __syncthreads();
        sm[t] += y;
        __syncthreads();
    }
    if (t < 98) part[t] = sm[t] - v;
}
__global__ void k_scanC(int* rowst, int* cur, const int* __restrict__ part) {
    int i = blockIdx.x * 256 + threadIdx.x;
    if (i >= N_NODES) return;
    int r = rowst[i] + part[i >> 10];
    rowst[i] = r; cur[i] = r;
}
__global__ void k_scatter(const int* __restrict__ src, const int* __restrict__ dst,
                          int* cur, int* csr) {
    int e = blockIdx.x * 256 + threadIdx.x;
    if (e >= N_EDGES) return;
    int p = atomicAdd(&cur[dst[e]], 1);
    csr[p] = src[e];
}

// ---- agg2 via CSR: per-edge recompute h1[src] from 2 scalars, fp32 regs ----
__global__ __launch_bounds__(256) void k_agg2(const long long* __restrict__ agg1p, const float* __restrict__ x,
                                              const int* __restrict__ rowst,
                                              const int* __restrict__ csr,
                                              const float* __restrict__ Wr1, const float* __restrict__ Wo1,
                                              const float* __restrict__ br1, unsigned int* __restrict__ xcat_u32) {
    const int wave = threadIdx.x >> 6, lane = threadIdx.x & 63;
    const int d0 = 2 * lane, d1 = 2 * lane + 1;
    const float u0 = Wr1[d0], u1 = Wr1[d1];
    const float v0 = Wo1[d0], v1 = Wo1[d1];
    const float c0 = br1[d0], c1 = br1[d1];
    int wid = blockIdx.x * 4 + wave;
    int nw = gridDim.x * 4;
    for (int i = wid; i < NPAD; i += nw) {
        float a0 = 0.f, a1 = 0.f;
        if (i < N_NODES) {
            long long pv = agg1p[i];
            int dg = pk_deg(pv), st = rowst[i];
            for (int base = 0; base < dg; base += 64) {
                float av = 0.f, xv = 0.f;
                int e = base + lane;
                if (e < dg) { int s = csr[st + e]; av = pk_agg(agg1p[s]); xv = x[s]; }
                int cnt = min(64, dg - base);
                for (int j = 0; j < cnt; ++j) {
                    float aj = __shfl(av, j);
                    float xj = __shfl(xv, j);
                    a0 += fmaxf(fmaf(aj, u0, fmaf(xj, v0, c0)), 0.f);
                    a1 += fmaxf(fmaf(aj, u1, fmaf(xj, v1, c1)), 0.f);
                }
            }
        }
        unsigned int w = (unsigned)f2bfu(a0) | ((unsigned)f2bfu(a1) << 16);
        xcat_u32[(size_t)i * 128 + lane] = w;
    }
}

// ---- Wcat^T (bf16): Wt[c][k] = (k<128 ? W_rel2[k][c] : W_root2[k-128][c]) ----
__global__ void k_wt(const float* __restrict__ Wr2, const float* __restrict__ Wo2,
                     unsigned short* __restrict__ Wt) {
    int gid = blockIdx.x * 256 + threadIdx.x;   // 65536
    int k = gid & 255, c = gid >> 8;
    float v = (k < 128) ? Wr2[k * 256 + c] : Wo2[(k - 128) * 256 + c];
    Wt[c * 256 + k] = f2bfu(v);
}

// ---- layer-2 GEMM: h2 = relu(Xcat @ Wcat + b2), bf16 MFMA; stores h2 TRANSPOSED ----
// 128x128 tile/block, 4 waves of 64x64; A,B staged via global_load_lds (dbuf, 32KB).
// LDS rows are 64B; source pre-swizzled with XOR ((row&3)<<4), reads apply same XOR.
__global__ __launch_bounds__(256) void k_gemm(const short* __restrict__ Xcat, const short* __restrict__ Wt,
                                              const float* __restrict__ b2, unsigned short* __restrict__ h2t) {
    __shared__ short Als[2][4096];   // [buf][128 rows x 32 k] = 8KB per buf
    __shared__ short Bls[2][4096];
    const int wave = threadIdx.x >> 6, lane = threadIdx.x & 63;
    const int r0 = blockIdx.x * 128;
    const int c0 = blockIdx.y * 128;
    const int wr = wave >> 1, wc = wave & 1;

    // staging: 512 granules of 16B per tile; granule g -> row=g>>2, slot=g&3
    const int g0 = wave * 64 + lane;             // call 0
    const int g1 = g0 + 256;                     // call 1
    const int ar0 = g0 >> 2, as0 = (g0 & 3) * 16;
    const int ar1 = g1 >> 2, as1 = (g1 & 3) * 16;
    const char* asrc0 = (const char*)Xcat + (size_t)(r0 + ar0) * 512 + (as0 ^ ((ar0 & 3) << 4));
    const char* asrc1 = (const char*)Xcat + (size_t)(r0 + ar1) * 512 + (as1 ^ ((ar1 & 3) << 4));
    const char* bsrc0 = (const char*)Wt   + (size_t)(c0 + ar0) * 512 + (as0 ^ ((ar0 & 3) << 4));
    const char* bsrc1 = (const char*)Wt   + (size_t)(c0 + ar1) * 512 + (as1 ^ ((ar1 & 3) << 4));
    const int ldsOff0 = wave * 512;              // shorts (granule*8)
    const int ldsOff1 = wave * 512 + 2048;

    // fragment read offsets (shorts): row*32 + ((lkb ^ ((lr&3)<<4))>>1)
    const int lr = lane & 15;
    const int lkb = (lane >> 4) << 4;            // byte {0,16,32,48}
    const int swz = (lr & 3) << 4;
    const int abase = ((wr * 64 + lr) * 64 + (lkb ^ swz)) >> 1;
    const int bbase = ((wc * 64 + lr) * 64 + (lkb ^ swz)) >> 1;

    f32x4 acc[4][4];
    #pragma unroll
    for (int m = 0; m < 4; ++m)
        #pragma unroll
        for (int t = 0; t < 4; ++t) acc[m][t] = (f32x4){0.f, 0.f, 0.f, 0.f};

    int koff = 0;
    load_lds16(asrc0, &Als[0][ldsOff0]);
    load_lds16(asrc1, &Als[0][ldsOff1]);
    load_lds16(bsrc0, &Bls[0][ldsOff0]);
    load_lds16(bsrc1, &Bls[0][ldsOff1]);
    __syncthreads();

    #pragma unroll
    for (int step = 0; step < 8; ++step) {
        const int cur = step & 1;
        if (step < 7) {
            koff += 64;
            load_lds16(asrc0 + koff, &Als[cur ^ 1][ldsOff0]);
            load_lds16(asrc1 + koff, &Als[cur ^ 1][ldsOff1]);
            load_lds16(bsrc0 + koff, &Bls[cur ^ 1][ldsOff0]);
            load_lds16(bsrc1 + koff, &Bls[cur ^ 1][ldsOff1]);
        }
        bf16x8 a[4], b[4];
        #pragma unroll
        for (int m = 0; m < 4; ++m) a[m] = *(const bf16x8*)&Als[cur][abase + m * 512];
        #pragma unroll
        for (int t = 0; t < 4; ++t) b[t] = *(const bf16x8*)&Bls[cur][bbase + t * 512];
        #pragma unroll
        for (int m = 0; m < 4; ++m)
            #pragma unroll
            for (int t = 0; t < 4; ++t)
                acc[m][t] = __builtin_amdgcn_mfma_f32_16x16x32_bf16(a[m], b[t], acc[m][t], 0, 0, 0);
        __syncthreads();
    }

    const int rb = (lane >> 4) * 4;
    #pragma unroll
    for (int m = 0; m < 4; ++m) {
        int row = r0 + wr * 64 + m * 16 + rb;
        #pragma unroll
        for (int t = 0; t < 4; ++t) {
            int col = c0 + wc * 64 + t * 16 + lr;
            float bias = b2[col];
            u16x4 w;
            #pragma unroll
            for (int j = 0; j < 4; ++j)
                w[j] = f2bfu(fmaxf(acc[m][t][j] + bias, 0.f));
            *(u16x4*)(h2t + (size_t)col * NPAD + row) = w;   // transposed store, 8B/lane
        }
    }
}

// ---- count-matrix build: edges -> Mt (f32 atomics), rows 0..63 ----
__global__ void k_mbedges(const int* __restrict__ src, const int* __restrict__ dst,
                          const int* __restrict__ batch, float* __restrict__ mt) {
    int e = blockIdx.x * 256 + threadIdx.x;
    if (e >= N_EDGES) return;
    int g = batch[dst[e]];
    atomicAdd(&mt[(size_t)g * NPAD + src[e]], 1.f);
}

// ---- indicator rows 64..127 (bf16, direct store) + per-graph node counts ----
__global__ __launch_bounds__(256) void k_mbnodes(const int* __restrict__ batch,
                                                 unsigned short* __restrict__ mtb, float* cntf) {
    __shared__ float lc[NG];
    int t = threadIdx.x;
    if (t < NG) lc[t] = 0.f;
    __syncthreads();
    int i = blockIdx.x * 256 + t;
    if (i < N_NODES) {
        int g = batch[i];
        mtb[(size_t)(64 + g) * NPAD + i] = 0x3F80;   // bf16 1.0
        atomicAdd(&lc[g], 1.f);
    }
    __syncthreads();
    if (t < NG) atomicAdd(&cntf[t], lc[t]);
}

// ---- convert count rows f32 -> bf16 (rows 0..63 of Mtb; writes ALL elements) ----
__global__ void k_mconv(const float* __restrict__ mt, unsigned short* __restrict__ mtb) {
    size_t base = ((size_t)blockIdx.x * 256 + threadIdx.x) * 8;   // 64*NPAD total, exact
    f32x4 a = *(const f32x4*)(mt + base);
    f32x4 b = *(const f32x4*)(mt + base + 4);
    u16x8 w;
    #pragma unroll
    for (int j = 0; j < 4; ++j) { w[j] = f2bfu(a[j]); w[4 + j] = f2bfu(b[j]); }
    *(u16x8*)(mtb + base) = w;
}

// ---- pooling GEMM: Pcat[128][256] += Mtb[128][K-slice] @ h2t^T, MFMA ----
// 64x64 per wave, block = (M 2x64) x (N 2x64), grid (196 K-slices of 512, 2 col-halves)
__global__ __launch_bounds__(256) void k_pool_gemm(const short* __restrict__ mtb,
                                                   const short* __restrict__ h2t,
                                                   float* __restrict__ pcat) {
    const int wave = threadIdx.x >> 6, lane = threadIdx.x & 63;
    const int m0 = (wave >> 1) * 64;
    const int c0 = blockIdx.y * 128 + (wave & 1) * 64;
    const int lr = lane & 15;
    const int lk = (lane >> 4) << 3;
    const int kbeg = blockIdx.x * 512;
    const int kend = min(kbeg + 512, NPAD);
    f32x4 acc[4][4];
    #pragma unroll
    for (int m = 0; m < 4; ++m)
        #pragma unroll
        for (int t = 0; t < 4; ++t) acc[m][t] = (f32x4){0.f, 0.f, 0.f, 0.f};
    const short* ap = mtb + (size_t)(m0 + lr) * NPAD + lk;
    const short* bp = h2t + (size_t)(c0 + lr) * NPAD + lk;
    for (int k0 = kbeg; k0 < kend; k0 += 32) {
        bf16x8 a[4], b[4];
        #pragma unroll
        for (int m = 0; m < 4; ++m) a[m] = *(const bf16x8*)(ap + (size_t)m * 16 * NPAD + k0);
        #pragma unroll
        for (int t = 0; t < 4; ++t) b[t] = *(const bf16x8*)(bp + (size_t)t * 16 * NPAD + k0);
        #pragma unroll
        for (int m = 0; m < 4; ++m)
            #pragma unroll
            for (int t = 0; t < 4; ++t)
                acc[m][t] = __builtin_amdgcn_mfma_f32_16x16x32_bf16(a[m], b[t], acc[m][t], 0, 0, 0);
    }
    const int rb = (lane >> 4) * 4;
    #pragma unroll
    for (int m = 0; m < 4; ++m) {
        int row = m0 + m * 16 + rb;
        #pragma unroll
        for (int t = 0; t < 4; ++t) {
            int col = c0 + t * 16 + lr;
            #pragma unroll
            for (int j = 0; j < 4; ++j)
                atomicAdd(&pcat[(size_t)(row + j) * 256 + col], acc[m][t][j]);
        }
    }
}

// ---- layer-3 on pooled sums + mean + L2 normalize ----
__global__ __launch_bounds__(256) void k_final(const float* __restrict__ Pagg, const float* __restrict__ Ph2,
                                               const float* __restrict__ cntf,
                                               const float* __restrict__ Wr3, const float* __restrict__ br3,
                                               const float* __restrict__ Wo3, float* __restrict__ out) {
    __shared__ float sa[256], sh[256];
    __shared__ float wred[4];
    int g = blockIdx.x, t = threadIdx.x;
    sa[t] = Pagg[g * 256 + t];
    sh[t] = Ph2[g * 256 + t];
    __syncthreads();
    float c0 = 0.f, c1 = 0.f;
    #pragma unroll 4
    for (int k = 0; k < 256; ++k) {
        float a = sa[k], h = sh[k];
        c0 = fmaf(a, Wr3[k * 512 + t], c0);
        c0 = fmaf(h, Wo3[k * 512 + t], c0);
        c1 = fmaf(a, Wr3[k * 512 + t + 256], c1);
        c1 = fmaf(h, Wo3[k * 512 + t + 256], c1);
    }
    float cnt = cntf[g];
    float inv = 1.f / fmaxf(cnt, 1.f);
    float p0 = (c0 + cnt * br3[t]) * inv;
    float p1 = (c1 + cnt * br3[t + 256]) * inv;
    float ss = p0 * p0 + p1 * p1;
    for (int o = 32; o > 0; o >>= 1) ss += __shfl_down(ss, o);
    int lane = t & 63;
    if (lane == 0) wred[t >> 6] = ss;
    __syncthreads();
    float tot = wred[0] + wred[1] + wred[2] + wred[3];
    float inv2 = 1.f / fmaxf(sqrtf(tot), 1e-12f);
    out[g * 512 + t]       = p0 * inv2;
    out[g * 512 + t + 256] = p1 * inv2;
}

extern "C" void kernel_launch(void* const* d_in, const int* in_sizes, int n_in,
                              void* d_out, int out_size, void* d_ws, size_t ws_size,
                              hipStream_t stream) {
    const float* x   = (const float*)d_in[0];
    const int*   ei  = (const int*)d_in[1];
    const int*   bat = (const int*)d_in[2];
    const float* Wr1 = (const float*)d_in[3];
    const float* br1 = (const float*)d_in[4];
    const float* Wo1 = (const float*)d_in[5];
    const float* Wr2 = (const float*)d_in[6];
    const float* br2 = (const float*)d_in[7];
    const float* Wo2 = (const float*)d_in[8];
    const float* Wr3 = (const float*)d_in[9];
    const float* br3 = (const float*)d_in[10];
    const float* Wo3 = (const float*)d_in[11];
    const int* src = ei;
    const int* dst = ei + N_EDGES;

    char* ws = (char*)d_ws;
    unsigned long long* agg1p = (unsigned long long*)(ws + OFF_AGG1P);
    int*            rowst= (int*)(ws + OFF_ROW);
    int*            cur  = (int*)(ws + OFF_CUR);
    int*            part = (int*)(ws + OFF_PART);
    int*            csr  = (int*)(ws + OFF_CSR);
    unsigned short* xcat = (unsigned short*)(ws + OFF_XCAT);
    float*          mt   = (float*)(ws + OFF_MT);
    unsigned short* mtb  = (unsigned short*)(ws + OFF_MTB);
    unsigned short* h2t  = (unsigned short*)(ws + OFF_H2T);
    unsigned short* wt   = (unsigned short*)(ws + OFF_WT);
    float*          pcat = (float*)(ws + OFF_PCAT);
    float*          cntf = (float*)(ws + OFF_CNT);

    hipMemsetAsync(agg1p, 0, (size_t)N_NODES * 8, stream);
    hipMemsetAsync(pcat, 0, 128 * 256 * 4 + 256, stream);   // Pcat + cnt

    k_edge1<<<(N_EDGES + 255) / 256, 256, 0, stream>>>(x, src, dst, agg1p);
    k_h1<<<(NPAD * 128) / 256, 256, 0, stream>>>((const long long*)agg1p, x, Wr1, Wo1, br1, xcat);
    k_scanA<<<98, 1024, 0, stream>>>((const long long*)agg1p, rowst, part);
    k_scanB<<<1, 128, 0, stream>>>(part);
    k_scanC<<<(N_NODES + 255) / 256, 256, 0, stream>>>(rowst, cur, part);
    k_scatter<<<(N_EDGES + 255) / 256, 256, 0, stream>>>(src, dst, cur, csr);
    k_agg2<<<1024, 256, 0, stream>>>((const long long*)agg1p, x, rowst, csr, Wr1, Wo1, br1, (unsigned int*)xcat);
    k_wt<<<256, 256, 0, stream>>>(Wr2, Wo2, wt);
    k_gemm<<<dim3(NPAD / 128, 2), 256, 0, stream>>>((const short*)xcat, (const short*)wt, br2, h2t);

    // Xcat dead -> reuse its 51.25 MB as Mt (f32 counts) + Mtb (bf16 [M;B])
    // zero only what's needed: mt (atomic base) + indicator rows of mtb
    hipMemsetAsync(ws + OFF_MT, 0, (size_t)64 * NPAD * 4, stream);
    hipMemsetAsync(ws + OFF_MTB + (size_t)64 * NPAD * 2, 0, (size_t)64 * NPAD * 2, stream);
    k_mbedges<<<(N_EDGES + 255) / 256, 256, 0, stream>>>(src, dst, bat, mt);
    k_mbnodes<<<(N_NODES + 255) / 256, 256, 0, stream>>>(bat, mtb, cntf);
    k_mconv<<<(64 * NPAD) / 2048, 256, 0, stream>>>(mt, mtb);
    k_pool_gemm<<<dim3(196, 2), 256, 0, stream>>>((const short*)mtb, (const short*)h2t, pcat);
    k_final<<<NG, 256, 0, stream>>>(pcat, pcat + 64 * 256, cntf, Wr3, br3, Wo3, (float*)d_out);
}

// Round 11
// 410.887 us; speedup vs baseline: 3.5576x; 1.0426x over previous
//
#include <hip/hip_runtime.h>

#define N_NODES 100000
#define N_EDGES 800000
#define NG      64
#define NPAD    100096   // 782 * 128 = 391 * 256

// ---------------- workspace layout (bytes) ----------------
// packed agg1: u64 per node = {deg:20 bits (hi), deg*2^24 + sum(x*2^20):44 bits (lo)}
constexpr size_t OFF_AGG1P = 0;                              // N u64 (800256)
constexpr size_t OFF_ROW  = OFF_AGG1P + 800256;              // N i32
constexpr size_t OFF_CUR  = OFF_ROW  + 400128;               // N i32 (unused, kept for layout)
constexpr size_t OFF_PART = OFF_CUR  + 400128;               // 128 i32
constexpr size_t OFF_CSR  = OFF_PART + 512;                  // E i32
constexpr size_t OFF_XCAT = OFF_CSR  + 3200000;              // NPAD*256 bf16 = 51,249,152 B
// rank[E] (i32, 3.2MB) aliases the head of XCAT: dead before k_h1/k_agg2 write xcat.
// after k_gemm, XCAT region is reused:
constexpr size_t OFF_MT   = OFF_XCAT;                        // 64*NPAD f32   = 25,624,576 B
constexpr size_t OFF_MTB  = OFF_XCAT + 25624576;             // 128*NPAD bf16 = 25,624,576 B
constexpr size_t OFF_H2T  = OFF_XCAT + (size_t)NPAD*256*2;   // 256*NPAD bf16 (transposed h2)
constexpr size_t OFF_WT   = OFF_H2T  + (size_t)NPAD*256*2;   // 256*256 bf16
constexpr size_t OFF_PCAT = OFF_WT   + 256*256*2;            // 128*256 f32
constexpr size_t OFF_CNT  = OFF_PCAT + 128*256*4;            // 64 f32

typedef __attribute__((ext_vector_type(8))) short bf16x8;
typedef __attribute__((ext_vector_type(8))) unsigned short u16x8;
typedef __attribute__((ext_vector_type(4))) unsigned short u16x4;
typedef __attribute__((ext_vector_type(4))) float f32x4;

__device__ __forceinline__ float bfu2f(unsigned short u) {
    return __uint_as_float(((unsigned)u) << 16);
}
__device__ __forceinline__ unsigned short f2bfu(float f) {
    unsigned u = __float_as_uint(f);
    unsigned r = (u + 0x7FFFu + ((u >> 16) & 1u)) >> 16;   // RNE
    return (unsigned short)r;
}

__device__ __forceinline__ void load_lds16(const void* g, void* l) {
    __builtin_amdgcn_global_load_lds(
        (const __attribute__((address_space(1))) unsigned int*)g,
        (__attribute__((address_space(3))) unsigned int*)l, 16, 0, 0);
}

#define PK_MASK ((1LL << 44) - 1)
__device__ __forceinline__ float pk_agg(long long v) {
    long long dg = v >> 44;
    return (float)((v & PK_MASK) - (dg << 24)) * (1.f / 1048576.f);
}
__device__ __forceinline__ int pk_deg(long long v) { return (int)(v >> 44); }

// ---- layer-1: ONE packed u64 atomic per edge; old value's deg field = edge rank ----
__global__ void k_edge1(const float* __restrict__ x, const int* __restrict__ src,
                        const int* __restrict__ dst, unsigned long long* __restrict__ agg1p,
                        int* __restrict__ rank) {
    int e = blockIdx.x * 256 + threadIdx.x;
    if (e >= N_EDGES) return;
    int s = src[e], d = dst[e];
    long long fixed = (long long)lrintf(x[s] * 1048576.f);
    unsigned long long add = (1ULL << 44) + (unsigned long long)(fixed + (1LL << 24));
    unsigned long long old = atomicAdd(&agg1p[d], add);
    rank[e] = (int)(old >> 44);            // # earlier edges with same dst
}

// ---- h1 = relu(a*u + x*v + b) -> Xcat[:,128:256] (bf16) ----
__global__ void k_h1(const long long* __restrict__ agg1p, const float* __restrict__ x,
                     const float* __restrict__ Wr1, const float* __restrict__ Wo1,
                     const float* __restrict__ br1, unsigned short* __restrict__ xcat) {
    int gid = blockIdx.x * 256 + threadIdx.x;
    if (gid >= NPAD * 128) return;
    int i = gid >> 7, d = gid & 127;
    float v = 0.f;
    if (i < N_NODES) {
        float a = pk_agg(agg1p[i]);
        v = fmaxf(fmaf(a, Wr1[d], fmaf(x[i], Wo1[d], br1[d])), 0.f);
    }
    xcat[(size_t)i * 256 + 128 + d] = f2bfu(v);
}

// ---- CSR build: block scan / partial scan / offset-fix / atomic-free scatter ----
__global__ __launch_bounds__(1024) void k_scanA(const long long* __restrict__ agg1p, int* rowst, int* part) {
    __shared__ int sm[1024];
    int t = threadIdx.x, i = blockIdx.x * 1024 + t;
    int v = (i < N_NODES) ? pk_deg(agg1p[i]) : 0;
    sm[t] = v; __syncthreads();
    for (int o = 1; o < 1024; o <<= 1) {
        int y = (t >= o) ? sm[t - o] : 0;
        __syncthreads();
        sm[t] += y;
        __syncthreads();
    }
    if (i < N_NODES) rowst[i] = sm[t] - v;
    if (t == 1023) part[blockIdx.x] = sm[t];
}
__global__ void k_scanB(int* part) {   // 1 block, 128 threads; NB = 98
    __shared__ int sm[128];
    int t = threadIdx.x;
    int v = (t < 98) ? part[t] : 0;
    sm[t] = v; __syncthreads();
    for (int o = 1; o < 128; o <<= 1) {
        int y = (t >= o) ? sm[t - o] : 0;
        __syncthreads();
        sm[t] += y;
        __syncthreads();
    }
    if (t < 98) part[t] = sm[t] - v;
}
__global__ void k_scanC(int* rowst, const int* __restrict__ part) {
    int i = blockIdx.x * 256 + threadIdx.x;
    if (i >= N_NODES) return;
    rowst[i] += part[i >> 10];
}
__global__ void k_scatter(const int* __restrict__ src, const int* __restrict__ dst,
                          const int* __restrict__ rank, const int* __restrict__ rowst,
                          int* __restrict__ csr) {
    int e = blockIdx.x * 256 + threadIdx.x;
    if (e >= N_EDGES) return;
    csr[rowst[dst[e]] + rank[e]] = src[e];   // no atomic: rank gives unique slot
}

// ---- agg2 via CSR: per-edge recompute h1[src] from 2 scalars, fp32 regs ----
__global__ __launch_bounds__(256) void k_agg2(const long long* __restrict__ agg1p, const float* __restrict__ x,
                                              const int* __restrict__ rowst,
                                              const int* __restrict__ csr,
                                              const float* __restrict__ Wr1, const float* __restrict__ Wo1,
                                              const float* __restrict__ br1, unsigned int* __restrict__ xcat_u32) {
    const int wave = threadIdx.x >> 6, lane = threadIdx.x & 63;
    const int d0 = 2 * lane, d1 = 2 * lane + 1;
    const float u0 = Wr1[d0], u1 = Wr1[d1];
    const float v0 = Wo1[d0], v1 = Wo1[d1];
    const float c0 = br1[d0], c1 = br1[d1];
    int wid = blockIdx.x * 4 + wave;
    int nw = gridDim.x * 4;
    for (int i = wid; i < NPAD; i += nw) {
        float a0 = 0.f, a1 = 0.f;
        if (i < N_NODES) {
            long long pv = agg1p[i];
            int dg = pk_deg(pv), st = rowst[i];
            for (int base = 0; base < dg; base += 64) {
                float av = 0.f, xv = 0.f;
                int e = base + lane;
                if (e < dg) { int s = csr[st + e]; av = pk_agg(agg1p[s]); xv = x[s]; }
                int cnt = min(64, dg - base);
                for (int j = 0; j < cnt; ++j) {
                    float aj = __shfl(av, j);
                    float xj = __shfl(xv, j);
                    a0 += fmaxf(fmaf(aj, u0, fmaf(xj, v0, c0)), 0.f);
                    a1 += fmaxf(fmaf(aj, u1, fmaf(xj, v1, c1)), 0.f);
                }
            }
        }
        unsigned int w = (unsigned)f2bfu(a0) | ((unsigned)f2bfu(a1) << 16);
        xcat_u32[(size_t)i * 128 + lane] = w;
    }
}

// ---- Wcat^T (bf16): Wt[c][k] = (k<128 ? W_rel2[k][c] : W_root2[k-128][c]) ----
__global__ void k_wt(const float* __restrict__ Wr2, const float* __restrict__ Wo2,
                     unsigned short* __restrict__ Wt) {
    int gid = blockIdx.x * 256 + threadIdx.x;   // 65536
    int k = gid & 255, c = gid >> 8;
    float v = (k < 128) ? Wr2[k * 256 + c] : Wo2[(k - 128) * 256 + c];
    Wt[c * 256 + k] = f2bfu(v);
}

// ---- layer-2 GEMM: h2 = relu(Xcat @ Wcat + b2), bf16 MFMA; stores h2 TRANSPOSED ----
// 128x128 tile/block, 4 waves of 64x64; A,B staged via global_load_lds (dbuf, 32KB).
// LDS rows are 64B; source pre-swizzled with XOR ((row&3)<<4), reads apply same XOR.
__global__ __launch_bounds__(256) void k_gemm(const short* __restrict__ Xcat, const short* __restrict__ Wt,
                                              const float* __restrict__ b2, unsigned short* __restrict__ h2t) {
    __shared__ short Als[2][4096];   // [buf][128 rows x 32 k] = 8KB per buf
    __shared__ short Bls[2][4096];
    const int wave = threadIdx.x >> 6, lane = threadIdx.x & 63;
    const int r0 = blockIdx.x * 128;
    const int c0 = blockIdx.y * 128;
    const int wr = wave >> 1, wc = wave & 1;

    // staging: 512 granules of 16B per tile; granule g -> row=g>>2, slot=g&3
    const int g0 = wave * 64 + lane;             // call 0
    const int g1 = g0 + 256;                     // call 1
    const int ar0 = g0 >> 2, as0 = (g0 & 3) * 16;
    const int ar1 = g1 >> 2, as1 = (g1 & 3) * 16;
    const char* asrc0 = (const char*)Xcat + (size_t)(r0 + ar0) * 512 + (as0 ^ ((ar0 & 3) << 4));
    const char* asrc1 = (const char*)Xcat + (size_t)(r0 + ar1) * 512 + (as1 ^ ((ar1 & 3) << 4));
    const char* bsrc0 = (const char*)Wt   + (size_t)(c0 + ar0) * 512 + (as0 ^ ((ar0 & 3) << 4));
    const char* bsrc1 = (const char*)Wt   + (size_t)(c0 + ar1) * 512 + (as1 ^ ((ar1 & 3) << 4));
    const int ldsOff0 = wave * 512;              // shorts (granule*8)
    const int ldsOff1 = wave * 512 + 2048;

    // fragment read offsets (shorts): row*32 + ((lkb ^ ((lr&3)<<4))>>1)
    const int lr = lane & 15;
    const int lkb = (lane >> 4) << 4;            // byte {0,16,32,48}
    const int swz = (lr & 3) << 4;
    const int abase = ((wr * 64 + lr) * 64 + (lkb ^ swz)) >> 1;
    const int bbase = ((wc * 64 + lr) * 64 + (lkb ^ swz)) >> 1;

    f32x4 acc[4][4];
    #pragma unroll
    for (int m = 0; m < 4; ++m)
        #pragma unroll
        for (int t = 0; t < 4; ++t) acc[m][t] = (f32x4){0.f, 0.f, 0.f, 0.f};

    int koff = 0;
    load_lds16(asrc0, &Als[0][ldsOff0]);
    load_lds16(asrc1, &Als[0][ldsOff1]);
    load_lds16(bsrc0, &Bls[0][ldsOff0]);
    load_lds16(bsrc1, &Bls[0][ldsOff1]);
    __syncthreads();

    #pragma unroll
    for (int step = 0; step < 8; ++step) {
        const int cur = step & 1;
        if (step < 7) {
            koff += 64;
            load_lds16(asrc0 + koff, &Als[cur ^ 1][ldsOff0]);
            load_lds16(asrc1 + koff, &Als[cur ^ 1][ldsOff1]);
            load_lds16(bsrc0 + koff, &Bls[cur ^ 1][ldsOff0]);
            load_lds16(bsrc1 + koff, &Bls[cur ^ 1][ldsOff1]);
        }
        bf16x8 a[4], b[4];
        #pragma unroll
        for (int m = 0; m < 4; ++m) a[m] = *(const bf16x8*)&Als[cur][abase + m * 512];
        #pragma unroll
        for (int t = 0; t < 4; ++t) b[t] = *(const bf16x8*)&Bls[cur][bbase + t * 512];
        #pragma unroll
        for (int m = 0; m < 4; ++m)
            #pragma unroll
            for (int t = 0; t < 4; ++t)
                acc[m][t] = __builtin_amdgcn_mfma_f32_16x16x32_bf16(a[m], b[t], acc[m][t], 0, 0, 0);
        __syncthreads();
    }

    const int rb = (lane >> 4) * 4;
    #pragma unroll
    for (int m = 0; m < 4; ++m) {
        int row = r0 + wr * 64 + m * 16 + rb;
        #pragma unroll
        for (int t = 0; t < 4; ++t) {
            int col = c0 + wc * 64 + t * 16 + lr;
            float bias = b2[col];
            u16x4 w;
            #pragma unroll
            for (int j = 0; j < 4; ++j)
                w[j] = f2bfu(fmaxf(acc[m][t][j] + bias, 0.f));
            *(u16x4*)(h2t + (size_t)col * NPAD + row) = w;   // transposed store, 8B/lane
        }
    }
}

// ---- count-matrix build: edges -> Mt (f32 atomics), rows 0..63 ----
__global__ void k_mbedges(const int* __restrict__ src, const int* __restrict__ dst,
                          const int* __restrict__ batch, float* __restrict__ mt) {
    int e = blockIdx.x * 256 + threadIdx.x;
    if (e >= N_EDGES) return;
    int g = batch[dst[e]];
    atomicAdd(&mt[(size_t)g * NPAD + src[e]], 1.f);
}

// ---- indicator rows 64..127 (bf16, direct store) + per-graph node counts ----
__global__ __launch_bounds__(256) void k_mbnodes(const int* __restrict__ batch,
                                                 unsigned short* __restrict__ mtb, float* cntf) {
    __shared__ float lc[NG];
    int t = threadIdx.x;
    if (t < NG) lc[t] = 0.f;
    __syncthreads();
    int i = blockIdx.x * 256 + t;
    if (i < N_NODES) {
        int g = batch[i];
        mtb[(size_t)(64 + g) * NPAD + i] = 0x3F80;   // bf16 1.0
        atomicAdd(&lc[g], 1.f);
    }
    __syncthreads();
    if (t < NG) atomicAdd(&cntf[t], lc[t]);
}

// ---- convert count rows f32 -> bf16 (rows 0..63 of Mtb; writes ALL elements) ----
__global__ void k_mconv(const float* __restrict__ mt, unsigned short* __restrict__ mtb) {
    size_t base = ((size_t)blockIdx.x * 256 + threadIdx.x) * 8;   // 64*NPAD total, exact
    f32x4 a = *(const f32x4*)(mt + base);
    f32x4 b = *(const f32x4*)(mt + base + 4);
    u16x8 w;
    #pragma unroll
    for (int j = 0; j < 4; ++j) { w[j] = f2bfu(a[j]); w[4 + j] = f2bfu(b[j]); }
    *(u16x8*)(mtb + base) = w;
}

// ---- pooling GEMM: Pcat[128][256] += Mtb[128][K-slice] @ h2t^T, MFMA ----
// 64x32 per wave, block = (M 2x64) x (C 2x32), grid (196 K-slices of 512, 4 col-quarters)
__global__ __launch_bounds__(256) void k_pool_gemm(const short* __restrict__ mtb,
                                                   const short* __restrict__ h2t,
                                                   float* __restrict__ pcat) {
    const int wave = threadIdx.x >> 6, lane = threadIdx.x & 63;
    const int m0 = (wave >> 1) * 64;
    const int c0 = blockIdx.y * 64 + (wave & 1) * 32;
    const int lr = lane & 15;
    const int lk = (lane >> 4) << 3;
    const int kbeg = blockIdx.x * 512;
    const int kend = min(kbeg + 512, NPAD);
    f32x4 acc[4][2];
    #pragma unroll
    for (int m = 0; m < 4; ++m)
        #pragma unroll
        for (int t = 0; t < 2; ++t) acc[m][t] = (f32x4){0.f, 0.f, 0.f, 0.f};
    const short* ap = mtb + (size_t)(m0 + lr) * NPAD + lk;
    const short* bp = h2t + (size_t)(c0 + lr) * NPAD + lk;
    for (int k0 = kbeg; k0 < kend; k0 += 32) {
        bf16x8 a[4], b[2];
        #pragma unroll
        for (int m = 0; m < 4; ++m) a[m] = *(const bf16x8*)(ap + (size_t)m * 16 * NPAD + k0);
        #pragma unroll
        for (int t = 0; t < 2; ++t) b[t] = *(const bf16x8*)(bp + (size_t)t * 16 * NPAD + k0);
        #pragma unroll
        for (int m = 0; m < 4; ++m)
            #pragma unroll
            for (int t = 0; t < 2; ++t)
                acc[m][t] = __builtin_amdgcn_mfma_f32_16x16x32_bf16(a[m], b[t], acc[m][t], 0, 0, 0);
    }
    const int rb = (lane >> 4) * 4;
    #pragma unroll
    for (int m = 0; m < 4; ++m) {
        int row = m0 + m * 16 + rb;
        #pragma unroll
        for (int t = 0; t < 2; ++t) {
            int col = c0 + t * 16 + lr;
            #pragma unroll
            for (int j = 0; j < 4; ++j)
                atomicAdd(&pcat[(size_t)(row + j) * 256 + col], acc[m][t][j]);
        }
    }
}

// ---- layer-3 on pooled sums + mean + L2 normalize ----
__global__ __launch_bounds__(256) void k_final(const float* __restrict__ Pagg, const float* __restrict__ Ph2,
                                               const float* __restrict__ cntf,
                                               const float* __restrict__ Wr3, const float* __restrict__ br3,
                                               const float* __restrict__ Wo3, float* __restrict__ out) {
    __shared__ float sa[256], sh[256];
    __shared__ float wred[4];
    int g = blockIdx.x, t = threadIdx.x;
    sa[t] = Pagg[g * 256 + t];
    sh[t] = Ph2[g * 256 + t];
    __syncthreads();
    float c0 = 0.f, c1 = 0.f;
    #pragma unroll 4
    for (int k = 0; k < 256; ++k) {
        float a = sa[k], h = sh[k];
        c0 = fmaf(a, Wr3[k * 512 + t], c0);
        c0 = fmaf(h, Wo3[k * 512 + t], c0);
        c1 = fmaf(a, Wr3[k * 512 + t + 256], c1);
        c1 = fmaf(h, Wo3[k * 512 + t + 256], c1);
    }
    float cnt = cntf[g];
    float inv = 1.f / fmaxf(cnt, 1.f);
    float p0 = (c0 + cnt * br3[t]) * inv;
    float p1 = (c1 + cnt * br3[t + 256]) * inv;
    float ss = p0 * p0 + p1 * p1;
    for (int o = 32; o > 0; o >>= 1) ss += __shfl_down(ss, o);
    int lane = t & 63;
    if (lane == 0) wred[t >> 6] = ss;
    __syncthreads();
    float tot = wred[0] + wred[1] + wred[2] + wred[3];
    float inv2 = 1.f / fmaxf(sqrtf(tot), 1e-12f);
    out[g * 512 + t]       = p0 * inv2;
    out[g * 512 + t + 256] = p1 * inv2;
}

extern "C" void kernel_launch(void* const* d_in, const int* in_sizes, int n_in,
                              void* d_out, int out_size, void* d_ws, size_t ws_size,
                              hipStream_t stream) {
    const float* x   = (const float*)d_in[0];
    const int*   ei  = (const int*)d_in[1];
    const int*   bat = (const int*)d_in[2];
    const float* Wr1 = (const float*)d_in[3];
    const float* br1 = (const float*)d_in[4];
    const float* Wo1 = (const float*)d_in[5];
    const float* Wr2 = (const float*)d_in[6];
    const float* br2 = (const float*)d_in[7];
    const float* Wo2 = (const float*)d_in[8];
    const float* Wr3 = (const float*)d_in[9];
    const float* br3 = (const float*)d_in[10];
    const float* Wo3 = (const float*)d_in[11];
    const int* src = ei;
    const int* dst = ei + N_EDGES;

    char* ws = (char*)d_ws;
    unsigned long long* agg1p = (unsigned long long*)(ws + OFF_AGG1P);
    int*            rowst= (int*)(ws + OFF_ROW);
    int*            part = (int*)(ws + OFF_PART);
    int*            csr  = (int*)(ws + OFF_CSR);
    int*            rank = (int*)(ws + OFF_XCAT);        // aliases xcat head; dead before k_h1
    unsigned short* xcat = (unsigned short*)(ws + OFF_XCAT);
    float*          mt   = (float*)(ws + OFF_MT);
    unsigned short* mtb  = (unsigned short*)(ws + OFF_MTB);
    unsigned short* h2t  = (unsigned short*)(ws + OFF_H2T);
    unsigned short* wt   = (unsigned short*)(ws + OFF_WT);
    float*          pcat = (float*)(ws + OFF_PCAT);
    float*          cntf = (float*)(ws + OFF_CNT);

    hipMemsetAsync(agg1p, 0, (size_t)N_NODES * 8, stream);
    hipMemsetAsync(pcat, 0, 128 * 256 * 4 + 256, stream);   // Pcat + cnt

    k_edge1<<<(N_EDGES + 255) / 256, 256, 0, stream>>>(x, src, dst, agg1p, rank);
    k_scanA<<<98, 1024, 0, stream>>>((const long long*)agg1p, rowst, part);
    k_scanB<<<1, 128, 0, stream>>>(part);
    k_scanC<<<(N_NODES + 255) / 256, 256, 0, stream>>>(rowst, part);
    k_scatter<<<(N_EDGES + 255) / 256, 256, 0, stream>>>(src, dst, rank, rowst, csr);
    // rank now dead -> xcat region free for k_h1 / k_agg2
    k_h1<<<(NPAD * 128) / 256, 256, 0, stream>>>((const long long*)agg1p, x, Wr1, Wo1, br1, xcat);
    k_agg2<<<1024, 256, 0, stream>>>((const long long*)agg1p, x, rowst, csr, Wr1, Wo1, br1, (unsigned int*)xcat);
    k_wt<<<256, 256, 0, stream>>>(Wr2, Wo2, wt);
    k_gemm<<<dim3(NPAD / 128, 2), 256, 0, stream>>>((const short*)xcat, (const short*)wt, br2, h2t);

    // Xcat dead -> reuse its 51.25 MB as Mt (f32 counts) + Mtb (bf16 [M;B])
    // zero only what's needed: mt (atomic base) + indicator rows of mtb
    hipMemsetAsync(ws + OFF_MT, 0, (size_t)64 * NPAD * 4, stream);
    hipMemsetAsync(ws + OFF_MTB + (size_t)64 * NPAD * 2, 0, (size_t)64 * NPAD * 2, stream);
    k_mbedges<<<(N_EDGES + 255) / 256, 256, 0, stream>>>(src, dst, bat, mt);
    k_mbnodes<<<(N_NODES + 255) / 256, 256, 0, stream>>>(bat, mtb, cntf);
    k_mconv<<<(64 * NPAD) / 2048, 256, 0, stream>>>(mt, mtb);
    k_pool_gemm<<<dim3(196, 4), 256, 0, stream>>>((const short*)mtb, (const short*)h2t, pcat);
    k_final<<<NG, 256, 0, stream>>>(pcat, pcat + 64 * 256, cntf, Wr3, br3, Wo3, (float*)d_out);
}

// Round 12
// 386.486 us; speedup vs baseline: 3.7822x; 1.0631x over previous
//
#include <hip/hip_runtime.h>

#define N_NODES 100000
#define N_EDGES 800000
#define NG      64
#define NPAD    100096   // 782 * 128 = 391 * 256

// ---------------- workspace layout (bytes) ----------------
// packed agg1: u64 per node = {deg:20 bits (hi), deg*2^24 + sum(x*2^20):44 bits (lo)}
constexpr size_t OFF_AGG1P = 0;                              // N u64 (800256)
constexpr size_t OFF_ROW  = OFF_AGG1P + 800256;              // N i32
constexpr size_t OFF_CUR  = OFF_ROW  + 400128;               // N i32 (unused, kept for layout)
constexpr size_t OFF_PART = OFF_CUR  + 400128;               // 128 i32
constexpr size_t OFF_CSR  = OFF_PART + 512;                  // E i32
constexpr size_t OFF_XCAT = OFF_CSR  + 3200000;              // NPAD*256 bf16 = 51,249,152 B
// rank[E] (i32, 3.2MB) aliases the head of XCAT: dead before k_h1/k_agg2 write xcat.
// after k_gemm, XCAT region is reused:
constexpr size_t OFF_MT   = OFF_XCAT;                        // 64*NPAD f32   = 25,624,576 B
constexpr size_t OFF_MTB  = OFF_XCAT + 25624576;             // 128*NPAD bf16 = 25,624,576 B
constexpr size_t OFF_H2T  = OFF_XCAT + (size_t)NPAD*256*2;   // 256*NPAD bf16 (transposed h2)
constexpr size_t OFF_WT   = OFF_H2T  + (size_t)NPAD*256*2;   // 256*256 bf16
constexpr size_t OFF_PCAT = OFF_WT   + 256*256*2;            // 128*256 f32
constexpr size_t OFF_CNT  = OFF_PCAT + 128*256*4;            // 64 f32

typedef __attribute__((ext_vector_type(8))) short bf16x8;
typedef __attribute__((ext_vector_type(8))) unsigned short u16x8;
typedef __attribute__((ext_vector_type(4))) unsigned short u16x4;
typedef __attribute__((ext_vector_type(4))) float f32x4;

__device__ __forceinline__ float bfu2f(unsigned short u) {
    return __uint_as_float(((unsigned)u) << 16);
}
__device__ __forceinline__ unsigned short f2bfu(float f) {
    unsigned u = __float_as_uint(f);
    unsigned r = (u + 0x7FFFu + ((u >> 16) & 1u)) >> 16;   // RNE
    return (unsigned short)r;
}

__device__ __forceinline__ void load_lds16(const void* g, void* l) {
    __builtin_amdgcn_global_load_lds(
        (const __attribute__((address_space(1))) unsigned int*)g,
        (__attribute__((address_space(3))) unsigned int*)l, 16, 0, 0);
}

#define PK_MASK ((1LL << 44) - 1)
__device__ __forceinline__ float pk_agg(long long v) {
    long long dg = v >> 44;
    return (float)((v & PK_MASK) - (dg << 24)) * (1.f / 1048576.f);
}
__device__ __forceinline__ int pk_deg(long long v) { return (int)(v >> 44); }

// ---- layer-1: ONE packed u64 atomic per edge; old value's deg field = edge rank ----
__global__ void k_edge1(const float* __restrict__ x, const int* __restrict__ src,
                        const int* __restrict__ dst, unsigned long long* __restrict__ agg1p,
                        int* __restrict__ rank) {
    int e = blockIdx.x * 256 + threadIdx.x;
    if (e >= N_EDGES) return;
    int s = src[e], d = dst[e];
    long long fixed = (long long)lrintf(x[s] * 1048576.f);
    unsigned long long add = (1ULL << 44) + (unsigned long long)(fixed + (1LL << 24));
    unsigned long long old = atomicAdd(&agg1p[d], add);
    rank[e] = (int)(old >> 44);            // # earlier edges with same dst
}

// ---- h1 = relu(a*u + x*v + b) -> Xcat[:,128:256] (bf16) ----
__global__ void k_h1(const long long* __restrict__ agg1p, const float* __restrict__ x,
                     const float* __restrict__ Wr1, const float* __restrict__ Wo1,
                     const float* __restrict__ br1, unsigned short* __restrict__ xcat) {
    int gid = blockIdx.x * 256 + threadIdx.x;
    if (gid >= NPAD * 128) return;
    int i = gid >> 7, d = gid & 127;
    float v = 0.f;
    if (i < N_NODES) {
        float a = pk_agg(agg1p[i]);
        v = fmaxf(fmaf(a, Wr1[d], fmaf(x[i], Wo1[d], br1[d])), 0.f);
    }
    xcat[(size_t)i * 256 + 128 + d] = f2bfu(v);
}

// ---- CSR build: block scan / partial scan / offset-fix / atomic-free scatter ----
__global__ __launch_bounds__(1024) void k_scanA(const long long* __restrict__ agg1p, int* rowst, int* part) {
    __shared__ int sm[1024];
    int t = threadIdx.x, i = blockIdx.x * 1024 + t;
    int v = (i < N_NODES) ? pk_deg(agg1p[i]) : 0;
    sm[t] = v; __syncthreads();
    for (int o = 1; o < 1024; o <<= 1) {
        int y = (t >= o) ? sm[t - o] : 0;
        __syncthreads();
        sm[t] += y;
        __syncthreads();
    }
    if (i < N_NODES) rowst[i] = sm[t] - v;
    if (t == 1023) part[blockIdx.x] = sm[t];
}
__global__ void k_scanB(int* part) {   // 1 block, 128 threads; NB = 98
    __shared__ int sm[128];
    int t = threadIdx.x;
    int v = (t < 98) ? part[t] : 0;
    sm[t] = v; __syncthreads();
    for (int o = 1; o < 128; o <<= 1) {
        int y = (t >= o) ? sm[t - o] : 0;
        __syncthreads();
        sm[t] += y;
        __syncthreads();
    }
    if (t < 98) part[t] = sm[t] - v;
}
__global__ void k_scanC(int* rowst, const int* __restrict__ part) {
    int i = blockIdx.x * 256 + threadIdx.x;
    if (i >= N_NODES) return;
    rowst[i] += part[i >> 10];
}
__global__ void k_scatter(const int* __restrict__ src, const int* __restrict__ dst,
                          const int* __restrict__ rank, const int* __restrict__ rowst,
                          int* __restrict__ csr) {
    int e = blockIdx.x * 256 + threadIdx.x;
    if (e >= N_EDGES) return;
    csr[rowst[dst[e]] + rank[e]] = src[e];   // no atomic: rank gives unique slot
}

// ---- agg2 via CSR: per-edge recompute h1[src] from 2 scalars, fp32 regs ----
__global__ __launch_bounds__(256) void k_agg2(const long long* __restrict__ agg1p, const float* __restrict__ x,
                                              const int* __restrict__ rowst,
                                              const int* __restrict__ csr,
                                              const float* __restrict__ Wr1, const float* __restrict__ Wo1,
                                              const float* __restrict__ br1, unsigned int* __restrict__ xcat_u32) {
    const int wave = threadIdx.x >> 6, lane = threadIdx.x & 63;
    const int d0 = 2 * lane, d1 = 2 * lane + 1;
    const float u0 = Wr1[d0], u1 = Wr1[d1];
    const float v0 = Wo1[d0], v1 = Wo1[d1];
    const float c0 = br1[d0], c1 = br1[d1];
    int wid = blockIdx.x * 4 + wave;
    int nw = gridDim.x * 4;
    for (int i = wid; i < NPAD; i += nw) {
        float a0 = 0.f, a1 = 0.f;
        if (i < N_NODES) {
            long long pv = agg1p[i];
            int dg = pk_deg(pv), st = rowst[i];
            for (int base = 0; base < dg; base += 64) {
                float av = 0.f, xv = 0.f;
                int e = base + lane;
                if (e < dg) { int s = csr[st + e]; av = pk_agg(agg1p[s]); xv = x[s]; }
                int cnt = min(64, dg - base);
                for (int j = 0; j < cnt; ++j) {
                    float aj = __shfl(av, j);
                    float xj = __shfl(xv, j);
                    a0 += fmaxf(fmaf(aj, u0, fmaf(xj, v0, c0)), 0.f);
                    a1 += fmaxf(fmaf(aj, u1, fmaf(xj, v1, c1)), 0.f);
                }
            }
        }
        unsigned int w = (unsigned)f2bfu(a0) | ((unsigned)f2bfu(a1) << 16);
        xcat_u32[(size_t)i * 128 + lane] = w;
    }
}

// ---- Wcat^T (bf16): Wt[c][k] = (k<128 ? W_rel2[k][c] : W_root2[k-128][c]) ----
__global__ void k_wt(const float* __restrict__ Wr2, const float* __restrict__ Wo2,
                     unsigned short* __restrict__ Wt) {
    int gid = blockIdx.x * 256 + threadIdx.x;   // 65536
    int k = gid & 255, c = gid >> 8;
    float v = (k < 128) ? Wr2[k * 256 + c] : Wo2[(k - 128) * 256 + c];
    Wt[c * 256 + k] = f2bfu(v);
}

// ---- layer-2 GEMM: h2 = relu(Xcat @ Wcat + b2), bf16 MFMA; stores h2 TRANSPOSED ----
// 128x128 tile/block, 4 waves of 64x64; A,B staged via global_load_lds (dbuf, 32KB).
// LDS rows are 64B; source pre-swizzled with XOR ((row&3)<<4), reads apply same XOR.
__global__ __launch_bounds__(256) void k_gemm(const short* __restrict__ Xcat, const short* __restrict__ Wt,
                                              const float* __restrict__ b2, unsigned short* __restrict__ h2t) {
    __shared__ short Als[2][4096];   // [buf][128 rows x 32 k] = 8KB per buf
    __shared__ short Bls[2][4096];
    const int wave = threadIdx.x >> 6, lane = threadIdx.x & 63;
    const int r0 = blockIdx.x * 128;
    const int c0 = blockIdx.y * 128;
    const int wr = wave >> 1, wc = wave & 1;

    // staging: 512 granules of 16B per tile; granule g -> row=g>>2, slot=g&3
    const int g0 = wave * 64 + lane;             // call 0
    const int g1 = g0 + 256;                     // call 1
    const int ar0 = g0 >> 2, as0 = (g0 & 3) * 16;
    const int ar1 = g1 >> 2, as1 = (g1 & 3) * 16;
    const char* asrc0 = (const char*)Xcat + (size_t)(r0 + ar0) * 512 + (as0 ^ ((ar0 & 3) << 4));
    const char* asrc1 = (const char*)Xcat + (size_t)(r0 + ar1) * 512 + (as1 ^ ((ar1 & 3) << 4));
    const char* bsrc0 = (const char*)Wt   + (size_t)(c0 + ar0) * 512 + (as0 ^ ((ar0 & 3) << 4));
    const char* bsrc1 = (const char*)Wt   + (size_t)(c0 + ar1) * 512 + (as1 ^ ((ar1 & 3) << 4));
    const int ldsOff0 = wave * 512;              // shorts (granule*8)
    const int ldsOff1 = wave * 512 + 2048;

    // fragment read offsets (shorts): row*32 + ((lkb ^ ((lr&3)<<4))>>1)
    const int lr = lane & 15;
    const int lkb = (lane >> 4) << 4;            // byte {0,16,32,48}
    const int swz = (lr & 3) << 4;
    const int abase = ((wr * 64 + lr) * 64 + (lkb ^ swz)) >> 1;
    const int bbase = ((wc * 64 + lr) * 64 + (lkb ^ swz)) >> 1;

    f32x4 acc[4][4];
    #pragma unroll
    for (int m = 0; m < 4; ++m)
        #pragma unroll
        for (int t = 0; t < 4; ++t) acc[m][t] = (f32x4){0.f, 0.f, 0.f, 0.f};

    int koff = 0;
    load_lds16(asrc0, &Als[0][ldsOff0]);
    load_lds16(asrc1, &Als[0][ldsOff1]);
    load_lds16(bsrc0, &Bls[0][ldsOff0]);
    load_lds16(bsrc1, &Bls[0][ldsOff1]);
    __syncthreads();

    #pragma unroll
    for (int step = 0; step < 8; ++step) {
        const int cur = step & 1;
        if (step < 7) {
            koff += 64;
            load_lds16(asrc0 + koff, &Als[cur ^ 1][ldsOff0]);
            load_lds16(asrc1 + koff, &Als[cur ^ 1][ldsOff1]);
            load_lds16(bsrc0 + koff, &Bls[cur ^ 1][ldsOff0]);
            load_lds16(bsrc1 + koff, &Bls[cur ^ 1][ldsOff1]);
        }
        bf16x8 a[4], b[4];
        #pragma unroll
        for (int m = 0; m < 4; ++m) a[m] = *(const bf16x8*)&Als[cur][abase + m * 512];
        #pragma unroll
        for (int t = 0; t < 4; ++t) b[t] = *(const bf16x8*)&Bls[cur][bbase + t * 512];
        #pragma unroll
        for (int m = 0; m < 4; ++m)
            #pragma unroll
            for (int t = 0; t < 4; ++t)
                acc[m][t] = __builtin_amdgcn_mfma_f32_16x16x32_bf16(a[m], b[t], acc[m][t], 0, 0, 0);
        __syncthreads();
    }

    const int rb = (lane >> 4) * 4;
    #pragma unroll
    for (int m = 0; m < 4; ++m) {
        int row = r0 + wr * 64 + m * 16 + rb;
        #pragma unroll
        for (int t = 0; t < 4; ++t) {
            int col = c0 + wc * 64 + t * 16 + lr;
            float bias = b2[col];
            u16x4 w;
            #pragma unroll
            for (int j = 0; j < 4; ++j)
                w[j] = f2bfu(fmaxf(acc[m][t][j] + bias, 0.f));
            *(u16x4*)(h2t + (size_t)col * NPAD + row) = w;   // transposed store, 8B/lane
        }
    }
}

// ---- count-matrix build: edges -> Mt (f32 atomics), rows 0..63 ----
__global__ void k_mbedges(const int* __restrict__ src, const int* __restrict__ dst,
                          const int* __restrict__ batch, float* __restrict__ mt) {
    int e = blockIdx.x * 256 + threadIdx.x;
    if (e >= N_EDGES) return;
    int g = batch[dst[e]];
    atomicAdd(&mt[(size_t)g * NPAD + src[e]], 1.f);
}

// ---- indicator rows 64..127 (bf16, direct store) + per-graph node counts ----
__global__ __launch_bounds__(256) void k_mbnodes(const int* __restrict__ batch,
                                                 unsigned short* __restrict__ mtb, float* cntf) {
    __shared__ float lc[NG];
    int t = threadIdx.x;
    if (t < NG) lc[t] = 0.f;
    __syncthreads();
    int i = blockIdx.x * 256 + t;
    if (i < N_NODES) {
        int g = batch[i];
        mtb[(size_t)(64 + g) * NPAD + i] = 0x3F80;   // bf16 1.0
        atomicAdd(&lc[g], 1.f);
    }
    __syncthreads();
    if (t < NG) atomicAdd(&cntf[t], lc[t]);
}

// ---- convert count rows f32 -> bf16 (rows 0..63 of Mtb; writes ALL elements) ----
__global__ void k_mconv(const float* __restrict__ mt, unsigned short* __restrict__ mtb) {
    size_t base = ((size_t)blockIdx.x * 256 + threadIdx.x) * 8;   // 64*NPAD total, exact
    f32x4 a = *(const f32x4*)(mt + base);
    f32x4 b = *(const f32x4*)(mt + base + 4);
    u16x8 w;
    #pragma unroll
    for (int j = 0; j < 4; ++j) { w[j] = f2bfu(a[j]); w[4 + j] = f2bfu(b[j]); }
    *(u16x8*)(mtb + base) = w;
}

// ---- pooling GEMM: Pcat[128][256] += Mtb[128][Kslice] @ h2t^T ----
// ONE block owns the whole 128x256 output; 196 K-slices of 512; 8 waves of 64x64.
// A[128][64],B[256][64] double-buffered LDS via global_load_lds; slot^(row&7) swizzle.
__global__ __launch_bounds__(512) void k_pool_gemm(const short* __restrict__ mtb,
                                                   const short* __restrict__ h2t,
                                                   float* __restrict__ pcat) {
    __shared__ short Als[2][8192];    // [128 rows][64 k] = 16KB per buf
    __shared__ short Bls[2][16384];   // [256 rows][64 k] = 32KB per buf
    const int tid = threadIdx.x;
    const int wave = tid >> 6, lane = tid & 63;
    const int wr = wave >> 2, wc = wave & 3;        // 2x4 waves -> 64x64 tiles
    const int kbeg = blockIdx.x * 512;
    const int nsteps = (min(kbeg + 512, NPAD) - kbeg) >> 6;   // 8 (or 4 for last)

    // staging: granule g -> row g>>3, dest slot g&7, SRC slot (g&7)^(row&7)
    // A: 1024 granules (2 calls); B: 2048 granules (4 calls)
    const char* asrc[2]; const char* bsrc[4];
    int aoff[2], boff[4];
    #pragma unroll
    for (int c = 0; c < 2; ++c) {
        int g = c * 512 + tid, r = g >> 3, s = (g & 7) ^ (r & 7);
        asrc[c] = (const char*)mtb + ((size_t)r * NPAD + kbeg) * 2 + s * 16;
        aoff[c] = g * 8;
    }
    #pragma unroll
    for (int c = 0; c < 4; ++c) {
        int g = c * 512 + tid, r = g >> 3, s = (g & 7) ^ (r & 7);
        bsrc[c] = (const char*)h2t + ((size_t)r * NPAD + kbeg) * 2 + s * 16;
        boff[c] = g * 8;
    }

    // read offsets: row*64 + ((ksub*4+q)^(lr&7))*8 shorts
    const int lr = lane & 15, q = lane >> 4;
    const int sl0 = (q ^ (lr & 7)) * 8;            // ksub 0
    const int sl1 = ((4 + q) ^ (lr & 7)) * 8;      // ksub 1
    int abase[4], bbase[4];
    #pragma unroll
    for (int m = 0; m < 4; ++m) abase[m] = (wr * 64 + m * 16 + lr) * 64;
    #pragma unroll
    for (int t = 0; t < 4; ++t) bbase[t] = (wc * 64 + t * 16 + lr) * 64;

    f32x4 acc[4][4];
    #pragma unroll
    for (int m = 0; m < 4; ++m)
        #pragma unroll
        for (int t = 0; t < 4; ++t) acc[m][t] = (f32x4){0.f, 0.f, 0.f, 0.f};

    // prologue: stage step 0 into buf 0
    #pragma unroll
    for (int c = 0; c < 2; ++c) load_lds16(asrc[c], &Als[0][aoff[c]]);
    #pragma unroll
    for (int c = 0; c < 4; ++c) load_lds16(bsrc[c], &Bls[0][boff[c]]);
    __syncthreads();

    for (int s = 0; s < nsteps; ++s) {
        const int cur = s & 1;
        if (s + 1 < nsteps) {
            int koff = (s + 1) * 128;              // 64 shorts = 128 B along k
            #pragma unroll
            for (int c = 0; c < 2; ++c) load_lds16(asrc[c] + koff, &Als[cur ^ 1][aoff[c]]);
            #pragma unroll
            for (int c = 0; c < 4; ++c) load_lds16(bsrc[c] + koff, &Bls[cur ^ 1][boff[c]]);
        }
        #pragma unroll
        for (int ksub = 0; ksub < 2; ++ksub) {
            const int sl = ksub ? sl1 : sl0;
            bf16x8 a[4], b[4];
            #pragma unroll
            for (int m = 0; m < 4; ++m) a[m] = *(const bf16x8*)&Als[cur][abase[m] + sl];
            #pragma unroll
            for (int t = 0; t < 4; ++t) b[t] = *(const bf16x8*)&Bls[cur][bbase[t] + sl];
            #pragma unroll
            for (int m = 0; m < 4; ++m)
                #pragma unroll
                for (int t = 0; t < 4; ++t)
                    acc[m][t] = __builtin_amdgcn_mfma_f32_16x16x32_bf16(a[m], b[t], acc[m][t], 0, 0, 0);
        }
        __syncthreads();
    }

    const int rb = q * 4;
    #pragma unroll
    for (int m = 0; m < 4; ++m) {
        int row = wr * 64 + m * 16 + rb;
        #pragma unroll
        for (int t = 0; t < 4; ++t) {
            int col = wc * 64 + t * 16 + lr;
            #pragma unroll
            for (int j = 0; j < 4; ++j)
                atomicAdd(&pcat[(size_t)(row + j) * 256 + col], acc[m][t][j]);
        }
    }
}

// ---- layer-3 on pooled sums + mean + L2 normalize ----
__global__ __launch_bounds__(256) void k_final(const float* __restrict__ Pagg, const float* __restrict__ Ph2,
                                               const float* __restrict__ cntf,
                                               const float* __restrict__ Wr3, const float* __restrict__ br3,
                                               const float* __restrict__ Wo3, float* __restrict__ out) {
    __shared__ float sa[256], sh[256];
    __shared__ float wred[4];
    int g = blockIdx.x, t = threadIdx.x;
    sa[t] = Pagg[g * 256 + t];
    sh[t] = Ph2[g * 256 + t];
    __syncthreads();
    float c0 = 0.f, c1 = 0.f;
    #pragma unroll 4
    for (int k = 0; k < 256; ++k) {
        float a = sa[k], h = sh[k];
        c0 = fmaf(a, Wr3[k * 512 + t], c0);
        c0 = fmaf(h, Wo3[k * 512 + t], c0);
        c1 = fmaf(a, Wr3[k * 512 + t + 256], c1);
        c1 = fmaf(h, Wo3[k * 512 + t + 256], c1);
    }
    float cnt = cntf[g];
    float inv = 1.f / fmaxf(cnt, 1.f);
    float p0 = (c0 + cnt * br3[t]) * inv;
    float p1 = (c1 + cnt * br3[t + 256]) * inv;
    float ss = p0 * p0 + p1 * p1;
    for (int o = 32; o > 0; o >>= 1) ss += __shfl_down(ss, o);
    int lane = t & 63;
    if (lane == 0) wred[t >> 6] = ss;
    __syncthreads();
    float tot = wred[0] + wred[1] + wred[2] + wred[3];
    float inv2 = 1.f / fmaxf(sqrtf(tot), 1e-12f);
    out[g * 512 + t]       = p0 * inv2;
    out[g * 512 + t + 256] = p1 * inv2;
}

extern "C" void kernel_launch(void* const* d_in, const int* in_sizes, int n_in,
                              void* d_out, int out_size, void* d_ws, size_t ws_size,
                              hipStream_t stream) {
    const float* x   = (const float*)d_in[0];
    const int*   ei  = (const int*)d_in[1];
    const int*   bat = (const int*)d_in[2];
    const float* Wr1 = (const float*)d_in[3];
    const float* br1 = (const float*)d_in[4];
    const float* Wo1 = (const float*)d_in[5];
    const float* Wr2 = (const float*)d_in[6];
    const float* br2 = (const float*)d_in[7];
    const float* Wo2 = (const float*)d_in[8];
    const float* Wr3 = (const float*)d_in[9];
    const float* br3 = (const float*)d_in[10];
    const float* Wo3 = (const float*)d_in[11];
    const int* src = ei;
    const int* dst = ei + N_EDGES;

    char* ws = (char*)d_ws;
    unsigned long long* agg1p = (unsigned long long*)(ws + OFF_AGG1P);
    int*            rowst= (int*)(ws + OFF_ROW);
    int*            part = (int*)(ws + OFF_PART);
    int*            csr  = (int*)(ws + OFF_CSR);
    int*            rank = (int*)(ws + OFF_XCAT);        // aliases xcat head; dead before k_h1
    unsigned short* xcat = (unsigned short*)(ws + OFF_XCAT);
    float*          mt   = (float*)(ws + OFF_MT);
    unsigned short* mtb  = (unsigned short*)(ws + OFF_MTB);
    unsigned short* h2t  = (unsigned short*)(ws + OFF_H2T);
    unsigned short* wt   = (unsigned short*)(ws + OFF_WT);
    float*          pcat = (float*)(ws + OFF_PCAT);
    float*          cntf = (float*)(ws + OFF_CNT);

    hipMemsetAsync(agg1p, 0, (size_t)N_NODES * 8, stream);
    hipMemsetAsync(pcat, 0, 128 * 256 * 4 + 256, stream);   // Pcat + cnt

    k_edge1<<<(N_EDGES + 255) / 256, 256, 0, stream>>>(x, src, dst, agg1p, rank);
    k_scanA<<<98, 1024, 0, stream>>>((const long long*)agg1p, rowst, part);
    k_scanB<<<1, 128, 0, stream>>>(part);
    k_scanC<<<(N_NODES + 255) / 256, 256, 0, stream>>>(rowst, part);
    k_scatter<<<(N_EDGES + 255) / 256, 256, 0, stream>>>(src, dst, rank, rowst, csr);
    // rank now dead -> xcat region free for k_h1 / k_agg2
    k_h1<<<(NPAD * 128) / 256, 256, 0, stream>>>((const long long*)agg1p, x, Wr1, Wo1, br1, xcat);
    k_agg2<<<1024, 256, 0, stream>>>((const long long*)agg1p, x, rowst, csr, Wr1, Wo1, br1, (unsigned int*)xcat);
    k_wt<<<256, 256, 0, stream>>>(Wr2, Wo2, wt);
    k_gemm<<<dim3(NPAD / 128, 2), 256, 0, stream>>>((const short*)xcat, (const short*)wt, br2, h2t);

    // Xcat dead -> reuse its 51.25 MB as Mt (f32 counts) + Mtb (bf16 [M;B])
    // zero only what's needed: mt (atomic base) + indicator rows of mtb
    hipMemsetAsync(ws + OFF_MT, 0, (size_t)64 * NPAD * 4, stream);
    hipMemsetAsync(ws + OFF_MTB + (size_t)64 * NPAD * 2, 0, (size_t)64 * NPAD * 2, stream);
    k_mbedges<<<(N_EDGES + 255) / 256, 256, 0, stream>>>(src, dst, bat, mt);
    k_mbnodes<<<(N_NODES + 255) / 256, 256, 0, stream>>>(bat, mtb, cntf);
    k_mconv<<<(64 * NPAD) / 2048, 256, 0, stream>>>(mt, mtb);
    k_pool_gemm<<<196, 512, 0, stream>>>((const short*)mtb, (const short*)h2t, pcat);
    k_final<<<NG, 256, 0, stream>>>(pcat, pcat + 64 * 256, cntf, Wr3, br3, Wo3, (float*)d_out);
}

// Round 13
// 360.391 us; speedup vs baseline: 4.0561x; 1.0724x over previous
//
#include <hip/hip_runtime.h>

#define N_NODES 100000
#define N_EDGES 800000
#define NG      64
#define NPAD    100096   // 782 * 128 = 391 * 256

// ---------------- workspace layout (bytes) ----------------
// packed agg1: u64 per node = {deg:20 bits (hi), deg*2^24 + sum(x*2^20):44 bits (lo)}
constexpr size_t OFF_AGG1P = 0;                              // N u64 (800256)
constexpr size_t OFF_ROW  = OFF_AGG1P + 800256;              // N i32
constexpr size_t OFF_CUR  = OFF_ROW  + 400128;               // N i32 (unused, kept for layout)
constexpr size_t OFF_PART = OFF_CUR  + 400128;               // 128 i32
constexpr size_t OFF_CSR  = OFF_PART + 512;                  // E i32
constexpr size_t OFF_XCAT = OFF_CSR  + 3200000;              // NPAD*256 bf16 = 51,249,152 B
// rank[E] (i32, 3.2MB) aliases the head of XCAT: consumed by k_scatter before k_agg2 writes xcat.
// after k_gemm, XCAT region is reused:
constexpr size_t OFF_MT   = OFF_XCAT;                        // 64*NPAD f32   = 25,624,576 B
constexpr size_t OFF_MTB  = OFF_XCAT + 25624576;             // 128*NPAD bf16 = 25,624,576 B
constexpr size_t OFF_H2T  = OFF_XCAT + (size_t)NPAD*256*2;   // 256*NPAD bf16 (transposed h2)
constexpr size_t OFF_WT   = OFF_H2T  + (size_t)NPAD*256*2;   // 256*256 bf16
constexpr size_t OFF_PCAT = OFF_WT   + 256*256*2;            // 128*256 f32
constexpr size_t OFF_CNT  = OFF_PCAT + 128*256*4;            // 64 f32

typedef __attribute__((ext_vector_type(8))) short bf16x8;
typedef __attribute__((ext_vector_type(8))) unsigned short u16x8;
typedef __attribute__((ext_vector_type(4))) unsigned short u16x4;
typedef __attribute__((ext_vector_type(4))) float f32x4;

__device__ __forceinline__ float bfu2f(unsigned short u) {
    return __uint_as_float(((unsigned)u) << 16);
}
__device__ __forceinline__ unsigned short f2bfu(float f) {
    unsigned u = __float_as_uint(f);
    unsigned r = (u + 0x7FFFu + ((u >> 16) & 1u)) >> 16;   // RNE
    return (unsigned short)r;
}

__device__ __forceinline__ void load_lds16(const void* g, void* l) {
    __builtin_amdgcn_global_load_lds(
        (const __attribute__((address_space(1))) unsigned int*)g,
        (__attribute__((address_space(3))) unsigned int*)l, 16, 0, 0);
}

#define PK_MASK ((1LL << 44) - 1)
__device__ __forceinline__ float pk_agg(long long v) {
    long long dg = v >> 44;
    return (float)((v & PK_MASK) - (dg << 24)) * (1.f / 1048576.f);
}
__device__ __forceinline__ int pk_deg(long long v) { return (int)(v >> 44); }

// ---- layer-1: ONE packed u64 atomic per edge; old value's deg field = edge rank ----
__global__ void k_edge1(const float* __restrict__ x, const int* __restrict__ src,
                        const int* __restrict__ dst, unsigned long long* __restrict__ agg1p,
                        int* __restrict__ rank) {
    int e = blockIdx.x * 256 + threadIdx.x;
    if (e >= N_EDGES) return;
    int s = src[e], d = dst[e];
    long long fixed = (long long)lrintf(x[s] * 1048576.f);
    unsigned long long add = (1ULL << 44) + (unsigned long long)(fixed + (1LL << 24));
    unsigned long long old = atomicAdd(&agg1p[d], add);
    rank[e] = (int)(old >> 44);            // # earlier edges with same dst
}

// ---- CSR build: block scan / partial scan / atomic-free scatter (part folded in) ----
__global__ __launch_bounds__(1024) void k_scanA(const long long* __restrict__ agg1p, int* rowst, int* part) {
    __shared__ int sm[1024];
    int t = threadIdx.x, i = blockIdx.x * 1024 + t;
    int v = (i < N_NODES) ? pk_deg(agg1p[i]) : 0;
    sm[t] = v; __syncthreads();
    for (int o = 1; o < 1024; o <<= 1) {
        int y = (t >= o) ? sm[t - o] : 0;
        __syncthreads();
        sm[t] += y;
        __syncthreads();
    }
    if (i < N_NODES) rowst[i] = sm[t] - v;
    if (t == 1023) part[blockIdx.x] = sm[t];
}
__global__ void k_scanB(int* part) {   // 1 block, 128 threads; NB = 98
    __shared__ int sm[128];
    int t = threadIdx.x;
    int v = (t < 98) ? part[t] : 0;
    sm[t] = v; __syncthreads();
    for (int o = 1; o < 128; o <<= 1) {
        int y = (t >= o) ? sm[t - o] : 0;
        __syncthreads();
        sm[t] += y;
        __syncthreads();
    }
    if (t < 98) part[t] = sm[t] - v;
}
__global__ void k_scatter(const int* __restrict__ src, const int* __restrict__ dst,
                          const int* __restrict__ rank, const int* __restrict__ rowst,
                          const int* __restrict__ part, int* __restrict__ csr) {
    int e = blockIdx.x * 256 + threadIdx.x;
    if (e >= N_EDGES) return;
    int d = dst[e];
    csr[rowst[d] + part[d >> 10] + rank[e]] = src[e];   // no atomic: rank gives unique slot
}

// ---- agg2 via CSR + self-h1 fold: writes BOTH halves of Xcat ----
__global__ __launch_bounds__(256) void k_agg2(const long long* __restrict__ agg1p, const float* __restrict__ x,
                                              const int* __restrict__ rowst, const int* __restrict__ part,
                                              const int* __restrict__ csr,
                                              const float* __restrict__ Wr1, const float* __restrict__ Wo1,
                                              const float* __restrict__ br1, unsigned int* __restrict__ xcat_u32) {
    const int wave = threadIdx.x >> 6, lane = threadIdx.x & 63;
    const int d0 = 2 * lane, d1 = 2 * lane + 1;
    const float u0 = Wr1[d0], u1 = Wr1[d1];
    const float v0 = Wo1[d0], v1 = Wo1[d1];
    const float c0 = br1[d0], c1 = br1[d1];
    int wid = blockIdx.x * 4 + wave;
    int nw = gridDim.x * 4;
    for (int i = wid; i < NPAD; i += nw) {
        float a0 = 0.f, a1 = 0.f, h0 = 0.f, h1v = 0.f;
        if (i < N_NODES) {
            long long pv = agg1p[i];
            float ai = pk_agg(pv);
            float xi = x[i];
            h0  = fmaxf(fmaf(ai, u0, fmaf(xi, v0, c0)), 0.f);   // self h1 (cols 128:256)
            h1v = fmaxf(fmaf(ai, u1, fmaf(xi, v1, c1)), 0.f);
            int dg = pk_deg(pv), st = rowst[i] + part[i >> 10];
            for (int base = 0; base < dg; base += 64) {
                float av = 0.f, xv = 0.f;
                int e = base + lane;
                if (e < dg) { int s = csr[st + e]; av = pk_agg(agg1p[s]); xv = x[s]; }
                int cnt = min(64, dg - base);
                for (int j = 0; j < cnt; ++j) {
                    float aj = __shfl(av, j);
                    float xj = __shfl(xv, j);
                    a0 += fmaxf(fmaf(aj, u0, fmaf(xj, v0, c0)), 0.f);
                    a1 += fmaxf(fmaf(aj, u1, fmaf(xj, v1, c1)), 0.f);
                }
            }
        }
        xcat_u32[(size_t)i * 128 + lane]      = (unsigned)f2bfu(a0) | ((unsigned)f2bfu(a1) << 16);
        xcat_u32[(size_t)i * 128 + 64 + lane] = (unsigned)f2bfu(h0) | ((unsigned)f2bfu(h1v) << 16);
    }
}

// ---- Wcat^T (bf16): Wt[c][k] = (k<128 ? W_rel2[k][c] : W_root2[k-128][c]) ----
__global__ void k_wt(const float* __restrict__ Wr2, const float* __restrict__ Wo2,
                     unsigned short* __restrict__ Wt) {
    int gid = blockIdx.x * 256 + threadIdx.x;   // 65536
    int k = gid & 255, c = gid >> 8;
    float v = (k < 128) ? Wr2[k * 256 + c] : Wo2[(k - 128) * 256 + c];
    Wt[c * 256 + k] = f2bfu(v);
}

// ---- layer-2 GEMM: h2 = relu(Xcat @ Wcat + b2); h2 stored TRANSPOSED via LDS-staged epilogue ----
// 128x128 tile/block, 4 waves of 64x64; A,B staged via global_load_lds (dbuf, 32KB).
// After K-loop, LDS is reused to transpose the output tile for coalesced h2t stores.
__global__ __launch_bounds__(256) void k_gemm(const short* __restrict__ Xcat, const short* __restrict__ Wt,
                                              const float* __restrict__ b2, unsigned short* __restrict__ h2t) {
    __shared__ short lds[16384];     // 32 KB: [0..8191]=Als[2][4096], [8192..]=Bls[2][4096]; reused as store buf
    short* Als = lds;
    short* Bls = lds + 8192;
    const int wave = threadIdx.x >> 6, lane = threadIdx.x & 63;
    const int r0 = blockIdx.x * 128;
    const int c0g = blockIdx.y * 128;
    const int wr = wave >> 1, wc = wave & 1;

    // staging: 512 granules of 16B per tile; granule g -> row=g>>2, slot=g&3
    const int g0 = wave * 64 + lane;             // call 0
    const int g1 = g0 + 256;                     // call 1
    const int ar0 = g0 >> 2, as0 = (g0 & 3) * 16;
    const int ar1 = g1 >> 2, as1 = (g1 & 3) * 16;
    const char* asrc0 = (const char*)Xcat + (size_t)(r0 + ar0) * 512 + (as0 ^ ((ar0 & 3) << 4));
    const char* asrc1 = (const char*)Xcat + (size_t)(r0 + ar1) * 512 + (as1 ^ ((ar1 & 3) << 4));
    const char* bsrc0 = (const char*)Wt   + (size_t)(c0g + ar0) * 512 + (as0 ^ ((ar0 & 3) << 4));
    const char* bsrc1 = (const char*)Wt   + (size_t)(c0g + ar1) * 512 + (as1 ^ ((ar1 & 3) << 4));
    const int ldsOff0 = wave * 512;              // shorts (granule*8)
    const int ldsOff1 = wave * 512 + 2048;

    // fragment read offsets (shorts): row*32 + ((lkb ^ ((lr&3)<<4))>>1)
    const int lr = lane & 15;
    const int q  = lane >> 4;
    const int lkb = q << 4;                      // byte {0,16,32,48}
    const int swz = (lr & 3) << 4;
    const int abase = ((wr * 64 + lr) * 64 + (lkb ^ swz)) >> 1;
    const int bbase = ((wc * 64 + lr) * 64 + (lkb ^ swz)) >> 1;

    f32x4 acc[4][4];
    #pragma unroll
    for (int m = 0; m < 4; ++m)
        #pragma unroll
        for (int t = 0; t < 4; ++t) acc[m][t] = (f32x4){0.f, 0.f, 0.f, 0.f};

    int koff = 0;
    load_lds16(asrc0, &Als[ldsOff0]);
    load_lds16(asrc1, &Als[ldsOff1]);
    load_lds16(bsrc0, &Bls[ldsOff0]);
    load_lds16(bsrc1, &Bls[ldsOff1]);
    __syncthreads();

    #pragma unroll
    for (int step = 0; step < 8; ++step) {
        const int cur = step & 1;
        if (step < 7) {
            koff += 64;
            load_lds16(asrc0 + koff, &Als[(cur ^ 1) * 4096 + ldsOff0]);
            load_lds16(asrc1 + koff, &Als[(cur ^ 1) * 4096 + ldsOff1]);
            load_lds16(bsrc0 + koff, &Bls[(cur ^ 1) * 4096 + ldsOff0]);
            load_lds16(bsrc1 + koff, &Bls[(cur ^ 1) * 4096 + ldsOff1]);
        }
        bf16x8 a[4], b[4];
        #pragma unroll
        for (int m = 0; m < 4; ++m) a[m] = *(const bf16x8*)&Als[cur * 4096 + abase + m * 512];
        #pragma unroll
        for (int t = 0; t < 4; ++t) b[t] = *(const bf16x8*)&Bls[cur * 4096 + bbase + t * 512];
        #pragma unroll
        for (int m = 0; m < 4; ++m)
            #pragma unroll
            for (int t = 0; t < 4; ++t)
                acc[m][t] = __builtin_amdgcn_mfma_f32_16x16x32_bf16(a[m], b[t], acc[m][t], 0, 0, 0);
        __syncthreads();
    }

    // ---- epilogue: bias+relu -> bf16 -> LDS [col][row^((col&7)<<3)] -> coalesced h2t stores ----
    #pragma unroll
    for (int m = 0; m < 4; ++m) {
        int rowb = wr * 64 + m * 16 + q * 4;               // local row base (mult of 4)
        #pragma unroll
        for (int t = 0; t < 4; ++t) {
            int col = wc * 64 + t * 16 + lr;               // local col
            float bias = b2[c0g + col];
            u16x4 w;
            #pragma unroll
            for (int j = 0; j < 4; ++j)
                w[j] = f2bfu(fmaxf(acc[m][t][j] + bias, 0.f));
            *(u16x4*)&lds[col * 128 + (rowb ^ ((col & 7) << 3))] = w;
        }
    }
    __syncthreads();
    #pragma unroll
    for (int c = 0; c < 8; ++c) {
        int G = c * 256 + threadIdx.x;                     // 2048 granules
        int col = G >> 4, g = G & 15;
        u16x8 v = *(const u16x8*)&lds[col * 128 + ((g * 8) ^ ((col & 7) << 3))];
        *(u16x8*)&h2t[(size_t)(c0g + col) * NPAD + r0 + g * 8] = v;
    }
}

// ---- count-matrix build: edges -> Mt (f32 atomics), rows 0..63 ----
__global__ void k_mbedges(const int* __restrict__ src, const int* __restrict__ dst,
                          const int* __restrict__ batch, float* __restrict__ mt) {
    int e = blockIdx.x * 256 + threadIdx.x;
    if (e >= N_EDGES) return;
    int g = batch[dst[e]];
    atomicAdd(&mt[(size_t)g * NPAD + src[e]], 1.f);
}

// ---- indicator rows 64..127 (bf16, direct store) + per-graph node counts ----
__global__ __launch_bounds__(256) void k_mbnodes(const int* __restrict__ batch,
                                                 unsigned short* __restrict__ mtb, float* cntf) {
    __shared__ float lc[NG];
    int t = threadIdx.x;
    if (t < NG) lc[t] = 0.f;
    __syncthreads();
    int i = blockIdx.x * 256 + t;
    if (i < N_NODES) {
        int g = batch[i];
        mtb[(size_t)(64 + g) * NPAD + i] = 0x3F80;   // bf16 1.0
        atomicAdd(&lc[g], 1.f);
    }
    __syncthreads();
    if (t < NG) atomicAdd(&cntf[t], lc[t]);
}

// ---- convert count rows f32 -> bf16 (rows 0..63 of Mtb; writes ALL elements) ----
__global__ void k_mconv(const float* __restrict__ mt, unsigned short* __restrict__ mtb) {
    size_t base = ((size_t)blockIdx.x * 256 + threadIdx.x) * 8;   // 64*NPAD total, exact
    f32x4 a = *(const f32x4*)(mt + base);
    f32x4 b = *(const f32x4*)(mt + base + 4);
    u16x8 w;
    #pragma unroll
    for (int j = 0; j < 4; ++j) { w[j] = f2bfu(a[j]); w[4 + j] = f2bfu(b[j]); }
    *(u16x8*)(mtb + base) = w;
}

// ---- pooling GEMM: Pcat[128][256] += Mtb[128][Kslice] @ h2t^T ----
// ONE block owns the whole 128x256 output; 196 K-slices of 512; 8 waves of 64x64.
// A[128][64],B[256][64] double-buffered LDS via global_load_lds; slot^(row&7) swizzle.
__global__ __launch_bounds__(512) void k_pool_gemm(const short* __restrict__ mtb,
                                                   const short* __restrict__ h2t,
                                                   float* __restrict__ pcat) {
    __shared__ short Als[2][8192];    // [128 rows][64 k] = 16KB per buf
    __shared__ short Bls[2][16384];   // [256 rows][64 k] = 32KB per buf
    const int tid = threadIdx.x;
    const int wave = tid >> 6, lane = tid & 63;
    const int wr = wave >> 2, wc = wave & 3;        // 2x4 waves -> 64x64 tiles
    const int kbeg = blockIdx.x * 512;
    const int nsteps = (min(kbeg + 512, NPAD) - kbeg) >> 6;   // 8 (or 4 for last)

    // staging: granule g -> row g>>3, dest slot g&7, SRC slot (g&7)^(row&7)
    const char* asrc[2]; const char* bsrc[4];
    int aoff[2], boff[4];
    #pragma unroll
    for (int c = 0; c < 2; ++c) {
        int g = c * 512 + tid, r = g >> 3, s = (g & 7) ^ (r & 7);
        asrc[c] = (const char*)mtb + ((size_t)r * NPAD + kbeg) * 2 + s * 16;
        aoff[c] = g * 8;
    }
    #pragma unroll
    for (int c = 0; c < 4; ++c) {
        int g = c * 512 + tid, r = g >> 3, s = (g & 7) ^ (r & 7);
        bsrc[c] = (const char*)h2t + ((size_t)r * NPAD + kbeg) * 2 + s * 16;
        boff[c] = g * 8;
    }

    // read offsets: row*64 + ((ksub*4+q)^(lr&7))*8 shorts
    const int lr = lane & 15, q = lane >> 4;
    const int sl0 = (q ^ (lr & 7)) * 8;            // ksub 0
    const int sl1 = ((4 + q) ^ (lr & 7)) * 8;      // ksub 1
    int abase[4], bbase[4];
    #pragma unroll
    for (int m = 0; m < 4; ++m) abase[m] = (wr * 64 + m * 16 + lr) * 64;
    #pragma unroll
    for (int t = 0; t < 4; ++t) bbase[t] = (wc * 64 + t * 16 + lr) * 64;

    f32x4 acc[4][4];
    #pragma unroll
    for (int m = 0; m < 4; ++m)
        #pragma unroll
        for (int t = 0; t < 4; ++t) acc[m][t] = (f32x4){0.f, 0.f, 0.f, 0.f};

    #pragma unroll
    for (int c = 0; c < 2; ++c) load_lds16(asrc[c], &Als[0][aoff[c]]);
    #pragma unroll
    for (int c = 0; c < 4; ++c) load_lds16(bsrc[c], &Bls[0][boff[c]]);
    __syncthreads();

    for (int s = 0; s < nsteps; ++s) {
        const int cur = s & 1;
        if (s + 1 < nsteps) {
            int koff = (s + 1) * 128;              // 64 shorts = 128 B along k
            #pragma unroll
            for (int c = 0; c < 2; ++c) load_lds16(asrc[c] + koff, &Als[cur ^ 1][aoff[c]]);
            #pragma unroll
            for (int c = 0; c < 4; ++c) load_lds16(bsrc[c] + koff, &Bls[cur ^ 1][boff[c]]);
        }
        #pragma unroll
        for (int ksub = 0; ksub < 2; ++ksub) {
            const int sl = ksub ? sl1 : sl0;
            bf16x8 a[4], b[4];
            #pragma unroll
            for (int m = 0; m < 4; ++m) a[m] = *(const bf16x8*)&Als[cur][abase[m] + sl];
            #pragma unroll
            for (int t = 0; t < 4; ++t) b[t] = *(const bf16x8*)&Bls[cur][bbase[t] + sl];
            #pragma unroll
            for (int m = 0; m < 4; ++m)
                #pragma unroll
                for (int t = 0; t < 4; ++t)
                    acc[m][t] = __builtin_amdgcn_mfma_f32_16x16x32_bf16(a[m], b[t], acc[m][t], 0, 0, 0);
        }
        __syncthreads();
    }

    const int rb = q * 4;
    #pragma unroll
    for (int m = 0; m < 4; ++m) {
        int row = wr * 64 + m * 16 + rb;
        #pragma unroll
        for (int t = 0; t < 4; ++t) {
            int col = wc * 64 + t * 16 + lr;
            #pragma unroll
            for (int j = 0; j < 4; ++j)
                atomicAdd(&pcat[(size_t)(row + j) * 256 + col], acc[m][t][j]);
        }
    }
}

// ---- layer-3 on pooled sums + mean + L2 normalize ----
__global__ __launch_bounds__(256) void k_final(const float* __restrict__ Pagg, const float* __restrict__ Ph2,
                                               const float* __restrict__ cntf,
                                               const float* __restrict__ Wr3, const float* __restrict__ br3,
                                               const float* __restrict__ Wo3, float* __restrict__ out) {
    __shared__ float sa[256], sh[256];
    __shared__ float wred[4];
    int g = blockIdx.x, t = threadIdx.x;
    sa[t] = Pagg[g * 256 + t];
    sh[t] = Ph2[g * 256 + t];
    __syncthreads();
    float c0 = 0.f, c1 = 0.f;
    #pragma unroll 4
    for (int k = 0; k < 256; ++k) {
        float a = sa[k], h = sh[k];
        c0 = fmaf(a, Wr3[k * 512 + t], c0);
        c0 = fmaf(h, Wo3[k * 512 + t], c0);
        c1 = fmaf(a, Wr3[k * 512 + t + 256], c1);
        c1 = fmaf(h, Wo3[k * 512 + t + 256], c1);
    }
    float cnt = cntf[g];
    float inv = 1.f / fmaxf(cnt, 1.f);
    float p0 = (c0 + cnt * br3[t]) * inv;
    float p1 = (c1 + cnt * br3[t + 256]) * inv;
    float ss = p0 * p0 + p1 * p1;
    for (int o = 32; o > 0; o >>= 1) ss += __shfl_down(ss, o);
    int lane = t & 63;
    if (lane == 0) wred[t >> 6] = ss;
    __syncthreads();
    float tot = wred[0] + wred[1] + wred[2] + wred[3];
    float inv2 = 1.f / fmaxf(sqrtf(tot), 1e-12f);
    out[g * 512 + t]       = p0 * inv2;
    out[g * 512 + t + 256] = p1 * inv2;
}

extern "C" void kernel_launch(void* const* d_in, const int* in_sizes, int n_in,
                              void* d_out, int out_size, void* d_ws, size_t ws_size,
                              hipStream_t stream) {
    const float* x   = (const float*)d_in[0];
    const int*   ei  = (const int*)d_in[1];
    const int*   bat = (const int*)d_in[2];
    const float* Wr1 = (const float*)d_in[3];
    const float* br1 = (const float*)d_in[4];
    const float* Wo1 = (const float*)d_in[5];
    const float* Wr2 = (const float*)d_in[6];
    const float* br2 = (const float*)d_in[7];
    const float* Wo2 = (const float*)d_in[8];
    const float* Wr3 = (const float*)d_in[9];
    const float* br3 = (const float*)d_in[10];
    const float* Wo3 = (const float*)d_in[11];
    const int* src = ei;
    const int* dst = ei + N_EDGES;

    char* ws = (char*)d_ws;
    unsigned long long* agg1p = (unsigned long long*)(ws + OFF_AGG1P);
    int*            rowst= (int*)(ws + OFF_ROW);
    int*            part = (int*)(ws + OFF_PART);
    int*            csr  = (int*)(ws + OFF_CSR);
    int*            rank = (int*)(ws + OFF_XCAT);        // aliases xcat head; dead before k_agg2
    unsigned short* xcat = (unsigned short*)(ws + OFF_XCAT);
    float*          mt   = (float*)(ws + OFF_MT);
    unsigned short* mtb  = (unsigned short*)(ws + OFF_MTB);
    unsigned short* h2t  = (unsigned short*)(ws + OFF_H2T);
    unsigned short* wt   = (unsigned short*)(ws + OFF_WT);
    float*          pcat = (float*)(ws + OFF_PCAT);
    float*          cntf = (float*)(ws + OFF_CNT);

    hipMemsetAsync(agg1p, 0, (size_t)N_NODES * 8, stream);
    hipMemsetAsync(pcat, 0, 128 * 256 * 4 + 256, stream);   // Pcat + cnt

    k_edge1<<<(N_EDGES + 255) / 256, 256, 0, stream>>>(x, src, dst, agg1p, rank);
    k_scanA<<<98, 1024, 0, stream>>>((const long long*)agg1p, rowst, part);
    k_scanB<<<1, 128, 0, stream>>>(part);
    k_scatter<<<(N_EDGES + 255) / 256, 256, 0, stream>>>(src, dst, rank, rowst, part, csr);
    // rank now dead -> xcat region free for k_agg2 (writes both Xcat halves)
    k_agg2<<<1024, 256, 0, stream>>>((const long long*)agg1p, x, rowst, part, csr, Wr1, Wo1, br1, (unsigned int*)xcat);
    k_wt<<<256, 256, 0, stream>>>(Wr2, Wo2, wt);
    k_gemm<<<dim3(NPAD / 128, 2), 256, 0, stream>>>((const short*)xcat, (const short*)wt, br2, h2t);

    // Xcat dead -> reuse its 51.25 MB as Mt (f32 counts) + Mtb (bf16 [M;B])
    hipMemsetAsync(ws + OFF_MT, 0, (size_t)64 * NPAD * 4, stream);
    hipMemsetAsync(ws + OFF_MTB + (size_t)64 * NPAD * 2, 0, (size_t)64 * NPAD * 2, stream);
    k_mbedges<<<(N_EDGES + 255) / 256, 256, 0, stream>>>(src, dst, bat, mt);
    k_mbnodes<<<(N_NODES + 255) / 256, 256, 0, stream>>>(bat, mtb, cntf);
    k_mconv<<<(64 * NPAD) / 2048, 256, 0, stream>>>(mt, mtb);
    k_pool_gemm<<<196, 512, 0, stream>>>((const short*)mtb, (const short*)h2t, pcat);
    k_final<<<NG, 256, 0, stream>>>(pcat, pcat + 64 * 256, cntf, Wr3, br3, Wo3, (float*)d_out);
}